// Round 9
// baseline (519.766 us; speedup 1.0000x reference)
//
#include <hip/hip_runtime.h>
#include <hip/hip_cooperative_groups.h>

namespace cg = cooperative_groups;

#define B_ 4
#define C_ 4
#define V_ 262144
#define F_ 64
#define K_ 100
#define THETA 0.9f
#define TAU_ 0.1f
#define CAP2 4096

typedef unsigned long long ull;

// ---------------- workspace layout (bytes) ----------------
// cs2    : 0       .. 8192     (8 replicas x C x F f32)
// cnt    : 8192    .. 8208     (C f32)
// ctrl1  : 8208    .. 8240     (B*2 u32: T1, n_above)
// ctrl2  : 8240    .. 8272     (B*2 u32: P16, n_above2)
// ccount : 8272    .. 8288     (B u32)
// idxout : 8320    .. 9920     (B*K u32)
// hist2  : 10240   .. 14336    (B*256 u32)
// cbits  : 16384   .. 81920    (B*CAP2 u32)
// cidx   : 81920   .. 147456   (B*CAP2 u32)
// cntp   : 147456  .. 163840   (1024*4 u32 per-block count partials)
// hist1p : 163840  .. 688128   (1024*256 u16 per-block hist1 partials)
// mask16 : 688128  .. 1212416  (B*V/4 u16 packed 4-bit class masks)
// wbits  : 1212416 .. 5406720  (B*V u32 product-weight float bits)

// Fused: init + y->mask16/count-partials + proba->wbits/hist1-partials.
__global__ __launch_bounds__(256) void k_prep(const int* __restrict__ y,
                                              const float* __restrict__ proba,
                                              unsigned short* __restrict__ mask16,
                                              unsigned* __restrict__ cntp,
                                              unsigned short* __restrict__ hist1p,
                                              unsigned* __restrict__ wbits,
                                              float* __restrict__ cs2,
                                              unsigned* __restrict__ hist2,
                                              unsigned* __restrict__ ccount) {
    __shared__ unsigned lh[256];
    __shared__ unsigned wc[4][2];
    int blk = blockIdx.x;
    int tid = threadIdx.x;
    int wave = tid >> 6, lane = tid & 63;
    int b = blk >> 8;
    int i4 = ((blk & 255) << 8) | tid;   // float4-group in [0, V/4)

    lh[tid] = 0u;
    // folded init (arrays only consumed by LATER kernels -> no race)
    if (blk < 8) cs2[(blk << 8) | tid] = 0.f;
    else if (blk < 12) hist2[((blk - 8) << 8) | tid] = 0u;
    else if (blk == 12 && tid < 4) ccount[tid] = 0u;
    __syncthreads();

    // ---- y -> packed masks + per-block counts ----
    const int4* y0 = (const int4*)(y + ((size_t)(b * C_ + 0)) * V_);
    const int4* y1 = (const int4*)(y + ((size_t)(b * C_ + 1)) * V_);
    const int4* y2 = (const int4*)(y + ((size_t)(b * C_ + 2)) * V_);
    const int4* y3 = (const int4*)(y + ((size_t)(b * C_ + 3)) * V_);
    int4 ya = y0[i4], yb = y1[i4], yc = y2[i4], yd = y3[i4];

    unsigned n0 = (unsigned)(ya.x > 0) | ((unsigned)(yb.x > 0) << 1) | ((unsigned)(yc.x > 0) << 2) | ((unsigned)(yd.x > 0) << 3);
    unsigned n1 = (unsigned)(ya.y > 0) | ((unsigned)(yb.y > 0) << 1) | ((unsigned)(yc.y > 0) << 2) | ((unsigned)(yd.y > 0) << 3);
    unsigned n2 = (unsigned)(ya.z > 0) | ((unsigned)(yb.z > 0) << 1) | ((unsigned)(yc.z > 0) << 2) | ((unsigned)(yd.z > 0) << 3);
    unsigned n3 = (unsigned)(ya.w > 0) | ((unsigned)(yb.w > 0) << 1) | ((unsigned)(yc.w > 0) << 2) | ((unsigned)(yd.w > 0) << 3);
    mask16[(size_t)b * (V_ / 4) + i4] = (unsigned short)(n0 | (n1 << 4) | (n2 << 8) | (n3 << 12));

    unsigned p01 = ((unsigned)(ya.x > 0) + (ya.y > 0) + (ya.z > 0) + (ya.w > 0))
                 | (((unsigned)(yb.x > 0) + (yb.y > 0) + (yb.z > 0) + (yb.w > 0)) << 16);
    unsigned p23 = ((unsigned)(yc.x > 0) + (yc.y > 0) + (yc.z > 0) + (yc.w > 0))
                 | (((unsigned)(yd.x > 0) + (yd.y > 0) + (yd.z > 0) + (yd.w > 0)) << 16);
    #pragma unroll
    for (int o = 1; o < 64; o <<= 1) {
        p01 += __shfl_xor(p01, o, 64);
        p23 += __shfl_xor(p23, o, 64);
    }
    if (lane == 0) { wc[wave][0] = p01; wc[wave][1] = p23; }

    // ---- proba -> wbits + LDS hist1 ----
    const float* p0 = proba + (size_t)(b * C_) * V_;
    float4 qa = ((const float4*)p0)[i4];
    float4 qb = ((const float4*)(p0 + V_))[i4];
    float4 qc = ((const float4*)(p0 + 2 * V_))[i4];
    float4 qd = ((const float4*)(p0 + 3 * V_))[i4];
    uint4 wb;
    wb.x = __float_as_uint(((qa.x * qb.x) * qc.x) * qd.x);
    wb.y = __float_as_uint(((qa.y * qb.y) * qc.y) * qd.y);
    wb.z = __float_as_uint(((qa.z * qb.z) * qc.z) * qd.z);
    wb.w = __float_as_uint(((qa.w * qb.w) * qc.w) * qd.w);
    ((uint4*)wbits)[(size_t)b * (V_ / 4) + i4] = wb;
    atomicAdd(&lh[wb.x >> 24], 1u);
    atomicAdd(&lh[wb.y >> 24], 1u);
    atomicAdd(&lh[wb.z >> 24], 1u);
    atomicAdd(&lh[wb.w >> 24], 1u);
    __syncthreads();

    hist1p[(blk << 8) | tid] = (unsigned short)lh[tid];
    if (tid == 0) {
        unsigned q01 = wc[0][0] + wc[1][0] + wc[2][0] + wc[3][0];
        unsigned q23 = wc[0][1] + wc[1][1] + wc[2][1] + wc[3][1];
        unsigned* o4 = cntp + (blk << 2);
        o4[0] = q01 & 0xFFFFu; o4[1] = q01 >> 16;
        o4[2] = q23 & 0xFFFFu; o4[3] = q23 >> 16;
    }
}

// bitonic compare-exchange steps (descending sort, 512 virtual lanes,
// 8 keys/lane, p = (lane<<3)|r). Fully static-unrolled (rule #20).
#define XSTEP(kk_, k_, j_) { \
    _Pragma("unroll") \
    for (int r = 0; r < 8; ++r) { \
        ull o = __shfl_xor(kk_[r], (j_) >> 3, 64); \
        int p = (lane << 3) | r; \
        bool keepmax = (((p & (k_)) == 0) == ((p & (j_)) == 0)); \
        kk_[r] = (keepmax == (kk_[r] > o)) ? kk_[r] : o; \
    } }
#define LSTEP(kk_, k_, j_) { \
    _Pragma("unroll") \
    for (int r = 0; r < 8; ++r) { \
        if (!(r & (j_))) { \
            int p = (lane << 3) | r; \
            bool up = ((p & (k_)) == 0); \
            ull a = kk_[r], c = kk_[r | (j_)]; \
            ull mx = a > c ? a : c, mn = a > c ? c : a; \
            kk_[r] = up ? mx : mn; \
            kk_[r | (j_)] = up ? mn : mx; \
        } \
    } }

// ONE cooperative kernel: thresh0 -> hist2 -> thresh1 -> collect -> select.
// Replaces 5 launches (each ~5us dispatch overhead) with 4 grid syncs.
__global__ __launch_bounds__(256, 4) void k_topk(const unsigned short* __restrict__ hist1p,
                                                 const unsigned* __restrict__ cntp,
                                                 const unsigned* __restrict__ wbits,
                                                 unsigned* __restrict__ ctrl1,
                                                 unsigned* __restrict__ ctrl2,
                                                 float* __restrict__ cnt,
                                                 unsigned* __restrict__ hist2,
                                                 unsigned* __restrict__ ccount,
                                                 unsigned* __restrict__ cbits,
                                                 unsigned* __restrict__ cidx,
                                                 unsigned* __restrict__ idxout) {
    cg::grid_group grid = cg::this_grid();
    __shared__ unsigned lh[256];
    __shared__ unsigned bins[256];
    int blk = blockIdx.x;
    int tid = threadIdx.x;
    int wave = tid >> 6, lane = tid & 63;

    // ---- phase A: thresh0 (blocks 0..3) + cnt reduce (block 4) ----
    if (blk < 4) {
        int b = blk;
        unsigned s = 0;
        for (int c = 0; c < 256; ++c)
            s += hist1p[(((b << 8) | c) << 8) | tid];
        bins[tid] = s;
        __syncthreads();
        if (wave == 0) {
            int binbase = 255 - 4 * lane;
            unsigned c0 = bins[binbase], c1 = bins[binbase - 1], c2 = bins[binbase - 2], c3 = bins[binbase - 3];
            unsigned cnt4 = c0 + c1 + c2 + c3;
            unsigned pref = cnt4;
            #pragma unroll
            for (int o = 1; o < 64; o <<= 1) {
                unsigned u = __shfl_up(pref, o, 64);
                if (lane >= o) pref += u;
            }
            unsigned above = pref - cnt4;
            unsigned t = above;
            int found = -1; unsigned nab = 0;
            if (t + c0 >= K_)                { found = binbase;     nab = t; }
            else if (t + c0 + c1 >= K_)      { found = binbase - 1; nab = t + c0; }
            else if (t + c0 + c1 + c2 >= K_) { found = binbase - 2; nab = t + c0 + c1; }
            else if (t + cnt4 >= K_)         { found = binbase - 3; nab = t + c0 + c1 + c2; }
            if (found >= 0 && above < K_) {
                ctrl1[b * 2] = (unsigned)found;
                ctrl1[b * 2 + 1] = nab;
            }
        }
    } else if (blk == 4 && wave == 0) {
        unsigned s0 = 0, s1 = 0, s2 = 0, s3 = 0;
        #pragma unroll
        for (int r = 0; r < 16; ++r) {
            uint4 p = ((const uint4*)cntp)[(r << 6) | lane];
            s0 += p.x; s1 += p.y; s2 += p.z; s3 += p.w;
        }
        #pragma unroll
        for (int o = 1; o < 64; o <<= 1) {
            s0 += __shfl_xor(s0, o, 64);
            s1 += __shfl_xor(s1, o, 64);
            s2 += __shfl_xor(s2, o, 64);
            s3 += __shfl_xor(s3, o, 64);
        }
        if (lane == 0) {
            cnt[0] = (float)s0; cnt[1] = (float)s1;
            cnt[2] = (float)s2; cnt[3] = (float)s3;
        }
    }
    grid.sync();

    // ---- phase B: hist2 (all 1024 blocks) ----
    {
        lh[tid] = 0u;
        __syncthreads();
        int b = blk >> 8;
        int base = (blk & 255) << 10;
        unsigned T1 = ctrl1[b * 2];
        for (int it = 0; it < 4; ++it) {
            int v = base + tid + (it << 8);
            unsigned bits = wbits[(size_t)b * V_ + v];
            if ((bits >> 24) == T1) atomicAdd(&lh[(bits >> 16) & 0xFF], 1u);
        }
        __syncthreads();
        if (lh[tid]) atomicAdd(&hist2[b * 256 + tid], lh[tid]);
    }
    grid.sync();

    // ---- phase C: thresh1 (block 0; 4 waves = 4 batches) ----
    if (blk == 0) {
        int b = wave;
        const unsigned* h = hist2 + b * 256;
        unsigned base = ctrl1[b * 2 + 1];
        int binbase = 255 - 4 * lane;
        unsigned c0 = h[binbase], c1 = h[binbase - 1], c2 = h[binbase - 2], c3 = h[binbase - 3];
        unsigned cnt4 = c0 + c1 + c2 + c3;
        unsigned pref = cnt4;
        #pragma unroll
        for (int o = 1; o < 64; o <<= 1) {
            unsigned u = __shfl_up(pref, o, 64);
            if (lane >= o) pref += u;
        }
        unsigned above = base + pref - cnt4;
        unsigned t = above;
        int found = -1; unsigned nab = 0;
        if (t + c0 >= K_)                { found = binbase;     nab = t; }
        else if (t + c0 + c1 >= K_)      { found = binbase - 1; nab = t + c0; }
        else if (t + c0 + c1 + c2 >= K_) { found = binbase - 2; nab = t + c0 + c1; }
        else if (t + cnt4 >= K_)         { found = binbase - 3; nab = t + c0 + c1 + c2; }
        if (found >= 0 && above < K_) {
            ctrl2[b * 2] = (ctrl1[b * 2] << 8) | (unsigned)found;
            ctrl2[b * 2 + 1] = nab;
        }
    }
    grid.sync();

    // ---- phase D: collect (all 1024 blocks) ----
    {
        int b = blk >> 8;
        int base = (blk & 255) << 10;
        unsigned P16 = ctrl2[b * 2];
        for (int it = 0; it < 4; ++it) {
            int v = base + tid + (it << 8);
            unsigned bits = wbits[(size_t)b * V_ + v];
            if ((bits >> 16) >= P16) {
                unsigned pos = atomicAdd(&ccount[b], 1u);
                if (pos < CAP2) { cbits[b * CAP2 + pos] = bits; cidx[b * CAP2 + pos] = (unsigned)v; }
            }
        }
    }
    grid.sync();

    // ---- phase E: select (blocks 0..3, wave 0) ----
    if (blk < 4 && wave == 0) {
        int b = blk;
        unsigned nc = ccount[b];
        int n = (int)(nc < CAP2 ? nc : CAP2);
        if (n <= 512) {
            // 512-wide register bitonic, descending by (bits, ~idx)
            ull kk[8];
            #pragma unroll
            for (int r = 0; r < 8; ++r) {
                int p = (lane << 3) | r;
                kk[r] = (p < n) ? (((ull)cbits[b * CAP2 + p] << 32) | (unsigned)(~cidx[b * CAP2 + p])) : 0ull;
            }
            LSTEP(kk, 2, 1)
            LSTEP(kk, 4, 2) LSTEP(kk, 4, 1)
            LSTEP(kk, 8, 4) LSTEP(kk, 8, 2) LSTEP(kk, 8, 1)
            XSTEP(kk, 16, 8) LSTEP(kk, 16, 4) LSTEP(kk, 16, 2) LSTEP(kk, 16, 1)
            XSTEP(kk, 32, 16) XSTEP(kk, 32, 8) LSTEP(kk, 32, 4) LSTEP(kk, 32, 2) LSTEP(kk, 32, 1)
            XSTEP(kk, 64, 32) XSTEP(kk, 64, 16) XSTEP(kk, 64, 8) LSTEP(kk, 64, 4) LSTEP(kk, 64, 2) LSTEP(kk, 64, 1)
            XSTEP(kk, 128, 64) XSTEP(kk, 128, 32) XSTEP(kk, 128, 16) XSTEP(kk, 128, 8) LSTEP(kk, 128, 4) LSTEP(kk, 128, 2) LSTEP(kk, 128, 1)
            XSTEP(kk, 256, 128) XSTEP(kk, 256, 64) XSTEP(kk, 256, 32) XSTEP(kk, 256, 16) XSTEP(kk, 256, 8) LSTEP(kk, 256, 4) LSTEP(kk, 256, 2) LSTEP(kk, 256, 1)
            XSTEP(kk, 512, 256) XSTEP(kk, 512, 128) XSTEP(kk, 512, 64) XSTEP(kk, 512, 32) XSTEP(kk, 512, 16) XSTEP(kk, 512, 8) LSTEP(kk, 512, 4) LSTEP(kk, 512, 2) LSTEP(kk, 512, 1)
            #pragma unroll
            for (int r = 0; r < 8; ++r) {
                int p = (lane << 3) | r;
                if (p < K_) idxout[b * K_ + p] = ~(unsigned)(kk[r] & 0xFFFFFFFFull);
            }
        } else {
            // rare fallback: in-place selection over global candidate arrays
            for (int k = 0; k < K_; ++k) {
                ull m = 0ull; int ms = -1;
                for (int i = lane; i < n; i += 64) {
                    ull key = ((ull)cbits[b * CAP2 + i] << 32) | (unsigned)(~cidx[b * CAP2 + i]);
                    if (key > m) { m = key; ms = i; }
                }
                ull lm_ = m;
                #pragma unroll
                for (int o = 1; o < 64; o <<= 1) {
                    ull other = __shfl_xor(m, o, 64);
                    if (other > m) m = other;
                }
                if (ms >= 0 && lm_ == m) { cbits[b * CAP2 + ms] = 0u; cidx[b * CAP2 + ms] = 0xFFFFFFFFu; }
                if (lane == 0) idxout[b * K_ + k] = ~(unsigned)(m & 0xFFFFFFFFull);
            }
        }
    }
}

// class_sum: pure stream; masks from LDS; atomics spread over 8 cs replicas.
__global__ __launch_bounds__(256) void k_class_sum(const float* __restrict__ emb,
                                                   const unsigned short* __restrict__ mask16,
                                                   float* __restrict__ cs2) {
    __shared__ unsigned short smask[2048];
    int blk = blockIdx.x;
    int tid = threadIdx.x;
    int wave = tid >> 6, lane = tid & 63;
    int b = blk >> 9;
    int rem = blk & 511;
    int fgrp = rem >> 5;
    int s = rem & 31;
    int f = (fgrp << 2) | wave;

    ((uint4*)smask)[tid] = ((const uint4*)(mask16 + (size_t)b * (V_ / 4) + (s << 11)))[tid];
    __syncthreads();

    const float4* ep = (const float4*)emb + ((size_t)((b << 6) | f)) * (V_ / 4) + (s << 11);

    float a0 = 0.f, a1 = 0.f, a2 = 0.f, a3 = 0.f;
    #pragma unroll
    for (int o = 0; o < 4; ++o) {
        float4 e[8];
        unsigned mm[8];
        #pragma unroll
        for (int i = 0; i < 8; ++i) e[i] = ep[(((o << 3) | i) << 6) | lane];
        #pragma unroll
        for (int i = 0; i < 8; ++i) mm[i] = smask[(((o << 3) | i) << 6) | lane];
        #pragma unroll
        for (int i = 0; i < 8; ++i) {
            unsigned m = mm[i];
            float4 ev = e[i];
            a0 += ( m        & 1u ? ev.x : 0.f) + ((m >>  4) & 1u ? ev.y : 0.f)
                + ((m >>  8) & 1u ? ev.z : 0.f) + ((m >> 12) & 1u ? ev.w : 0.f);
            a1 += ((m >>  1) & 1u ? ev.x : 0.f) + ((m >>  5) & 1u ? ev.y : 0.f)
                + ((m >>  9) & 1u ? ev.z : 0.f) + ((m >> 13) & 1u ? ev.w : 0.f);
            a2 += ((m >>  2) & 1u ? ev.x : 0.f) + ((m >>  6) & 1u ? ev.y : 0.f)
                + ((m >> 10) & 1u ? ev.z : 0.f) + ((m >> 14) & 1u ? ev.w : 0.f);
            a3 += ((m >>  3) & 1u ? ev.x : 0.f) + ((m >>  7) & 1u ? ev.y : 0.f)
                + ((m >> 11) & 1u ? ev.z : 0.f) + ((m >> 15) & 1u ? ev.w : 0.f);
        }
    }
    #pragma unroll
    for (int o = 1; o < 64; o <<= 1) {
        a0 += __shfl_xor(a0, o, 64);
        a1 += __shfl_xor(a1, o, 64);
        a2 += __shfl_xor(a2, o, 64);
        a3 += __shfl_xor(a3, o, 64);
    }
    float av = (lane == 0) ? a0 : (lane == 1) ? a1 : (lane == 2) ? a2 : a3;
    if (lane < 4) atomicAdd(&cs2[((blk & 7) << 8) | (lane << 6) | f], av);
}

// final: one wave (64 lanes = F) per (b,k); sums the 8 cs replicas inline.
__global__ __launch_bounds__(64) void k_final(const float* __restrict__ emb,
                                              const int* __restrict__ y,
                                              const float* __restrict__ avg,
                                              const float* __restrict__ cs2,
                                              const float* __restrict__ cnt,
                                              const unsigned* __restrict__ idxout,
                                              float* __restrict__ out) {
    int blk = blockIdx.x;
    int b = blk / K_;
    int k = blk % K_;
    int lane = threadIdx.x;
    unsigned v = idxout[b * K_ + k];

    float e = emb[((size_t)(b * F_ + lane)) * V_ + v];

    int y0v = y[((size_t)(b * C_ + 0)) * V_ + v];
    int y1v = y[((size_t)(b * C_ + 1)) * V_ + v];
    int y2v = y[((size_t)(b * C_ + 2)) * V_ + v];
    int y3v = y[((size_t)(b * C_ + 3)) * V_ + v];
    int cm = (y0v > 0) ? 0 : ((y1v > 0) ? 1 : ((y2v > 0) ? 2 : ((y3v > 0) ? 3 : 0)));
    float sel = (cm == 0) ? 1.f : 0.f;

    float t = e / TAU_;
    float ssum = 0.f;
    #pragma unroll
    for (int c = 1; c < 4; ++c) {
        float cc = cnt[c];
        float csum = 0.f;
        #pragma unroll
        for (int rep = 0; rep < 8; ++rep) csum += cs2[(rep << 8) | (c << 6) | lane];
        float mean = csum / fmaxf(cc, 1.f);
        float av = avg[c * F_ + lane];
        float nar = (cc > 0.f) ? (av * (1.f - THETA) + mean * THETA) : av;
        ssum += expf(t * nar);
    }
    float term = -logf(ssum);
    #pragma unroll
    for (int o = 32; o > 0; o >>= 1) term += __shfl_down(term, o, 64);
    if (lane == 0) out[b * K_ + k] = term * sel;
}

extern "C" void kernel_launch(void* const* d_in, const int* in_sizes, int n_in,
                              void* d_out, int out_size, void* d_ws, size_t ws_size,
                              hipStream_t stream) {
    const float* proba = (const float*)d_in[0];
    const int* y = (const int*)d_in[1];
    const float* emb = (const float*)d_in[2];
    const float* avg = (const float*)d_in[3];
    float* out = (float*)d_out;

    char* ws = (char*)d_ws;
    float* cs2 = (float*)(ws + 0);
    float* cnt = (float*)(ws + 8192);
    unsigned* ctrl1 = (unsigned*)(ws + 8208);
    unsigned* ctrl2 = (unsigned*)(ws + 8240);
    unsigned* ccount = (unsigned*)(ws + 8272);
    unsigned* idxout = (unsigned*)(ws + 8320);
    unsigned* hist2 = (unsigned*)(ws + 10240);
    unsigned* cbits = (unsigned*)(ws + 16384);
    unsigned* cidx = (unsigned*)(ws + 81920);
    unsigned* cntp = (unsigned*)(ws + 147456);
    unsigned short* hist1p = (unsigned short*)(ws + 163840);
    unsigned short* mask16 = (unsigned short*)(ws + 688128);
    unsigned* wbits = (unsigned*)(ws + 1212416);

    k_prep<<<B_ * 256, 256, 0, stream>>>(y, proba, mask16, cntp, hist1p, wbits, cs2, hist2, ccount);

    void* args[] = {(void*)&hist1p, (void*)&cntp, (void*)&wbits, (void*)&ctrl1,
                    (void*)&ctrl2, (void*)&cnt, (void*)&hist2, (void*)&ccount,
                    (void*)&cbits, (void*)&cidx, (void*)&idxout};
    hipLaunchCooperativeKernel((void*)k_topk, dim3(1024), dim3(256), args, 0, stream);

    k_class_sum<<<2048, 256, 0, stream>>>(emb, mask16, cs2);
    k_final<<<B_ * K_, 64, 0, stream>>>(emb, y, avg, cs2, cnt, idxout, out);
}

// Round 10
// 321.220 us; speedup vs baseline: 1.6181x; 1.6181x over previous
//
#include <hip/hip_runtime.h>

#define B_ 4
#define C_ 4
#define V_ 262144
#define F_ 64
#define K_ 100
#define THETA 0.9f
#define TAU_ 0.1f
#define CAP2 4096

typedef unsigned long long ull;

// ---------------- workspace layout (bytes) ----------------
// cs2    : 0       .. 8192     (8 replicas x C x F f32)
// cnt    : 8192    .. 8208     (C f32)
// ctrl1  : 8208    .. 8240     (B*2 u32: T1, n_above)
// ctrl2  : 8240    .. 8272     (B*2 u32: P16, n_above2)
// ccount : 8272    .. 8288     (B u32)
// idxout : 8320    .. 9920     (B*K u32)
// hist2  : 10240   .. 14336    (B*256 u32)
// ctrs   : 14336   .. 14348    (3 u32 done-counters; memset to 0 each launch)
// cbits  : 16384   .. 81920    (B*CAP2 u32)
// cidx   : 81920   .. 147456   (B*CAP2 u32)
// cntp   : 147456  .. 163840   (1024*4 u32 per-block count partials)
// hist1p : 163840  .. 688128   (1024*256 u16 per-block hist1 partials)
// mask16 : 688128  .. 1212416  (B*V/4 u16 packed 4-bit class masks)
// wbits  : 1212416 .. 5406720  (B*V u32 product-weight float bits)

// descending-threshold scan over 256 bins, lane l owns bins 4l..4l+3 (g0..g3).
// returns via ctrl_out: {prefix | T, count strictly above T}. base = counts
// already known to be above all these bins.
__device__ __forceinline__ void scan_thresh(unsigned g0, unsigned g1, unsigned g2, unsigned g3,
                                            unsigned base, unsigned prefix_hi, int lane,
                                            unsigned* ctrl_out) {
    unsigned S = g0 + g1 + g2 + g3;
    unsigned pref = S;
    #pragma unroll
    for (int o = 1; o < 64; o <<= 1) {
        unsigned u = __shfl_down(pref, o, 64);
        if (lane + o < 64) pref += u;
    }
    unsigned ag = base + pref - S;   // strictly above bin 4*lane+3
    int T = -1; unsigned nab = 0;
    if (ag + g3 >= K_)                { T = 4 * lane + 3; nab = ag; }
    else if (ag + g3 + g2 >= K_)      { T = 4 * lane + 2; nab = ag + g3; }
    else if (ag + g3 + g2 + g1 >= K_) { T = 4 * lane + 1; nab = ag + g3 + g2; }
    else if (ag + S >= K_)            { T = 4 * lane;     nab = ag + g3 + g2 + g1; }
    if (T >= 0 && ag < K_) {
        ctrl_out[0] = (prefix_hi << 8) | (unsigned)T;
        ctrl_out[1] = nab;
    }
}

// Fused: init + y->mask16/count-partials + proba->wbits/hist1-partials.
// LAST block (decoupled, NOT grid.sync — round-9 lesson: grid.sync ~115us!)
// folds in thresh0 (wave w = batch w) + cnt reduce.
__global__ __launch_bounds__(256) void k_prep(const int* __restrict__ y,
                                              const float* __restrict__ proba,
                                              unsigned short* __restrict__ mask16,
                                              unsigned* __restrict__ cntp,
                                              unsigned short* __restrict__ hist1p,
                                              unsigned* __restrict__ wbits,
                                              float* __restrict__ cs2,
                                              unsigned* __restrict__ hist2,
                                              unsigned* __restrict__ ccount,
                                              unsigned* __restrict__ ctrl1,
                                              float* __restrict__ cnt,
                                              unsigned* __restrict__ ctr) {
    __shared__ unsigned lh[256];
    __shared__ unsigned wc[4][2];
    __shared__ unsigned lastFlag;
    int blk = blockIdx.x;
    int tid = threadIdx.x;
    int wave = tid >> 6, lane = tid & 63;
    int b = blk >> 8;
    int i4 = ((blk & 255) << 8) | tid;   // float4-group in [0, V/4)

    lh[tid] = 0u;
    // folded init (arrays only consumed by LATER kernels -> no race)
    if (blk < 8) cs2[(blk << 8) | tid] = 0.f;
    else if (blk < 12) hist2[((blk - 8) << 8) | tid] = 0u;
    else if (blk == 12 && tid < 4) ccount[tid] = 0u;
    __syncthreads();

    // ---- y -> packed masks + per-block counts ----
    const int4* y0 = (const int4*)(y + ((size_t)(b * C_ + 0)) * V_);
    const int4* y1 = (const int4*)(y + ((size_t)(b * C_ + 1)) * V_);
    const int4* y2 = (const int4*)(y + ((size_t)(b * C_ + 2)) * V_);
    const int4* y3 = (const int4*)(y + ((size_t)(b * C_ + 3)) * V_);
    int4 ya = y0[i4], yb = y1[i4], yc = y2[i4], yd = y3[i4];

    unsigned n0 = (unsigned)(ya.x > 0) | ((unsigned)(yb.x > 0) << 1) | ((unsigned)(yc.x > 0) << 2) | ((unsigned)(yd.x > 0) << 3);
    unsigned n1 = (unsigned)(ya.y > 0) | ((unsigned)(yb.y > 0) << 1) | ((unsigned)(yc.y > 0) << 2) | ((unsigned)(yd.y > 0) << 3);
    unsigned n2 = (unsigned)(ya.z > 0) | ((unsigned)(yb.z > 0) << 1) | ((unsigned)(yc.z > 0) << 2) | ((unsigned)(yd.z > 0) << 3);
    unsigned n3 = (unsigned)(ya.w > 0) | ((unsigned)(yb.w > 0) << 1) | ((unsigned)(yc.w > 0) << 2) | ((unsigned)(yd.w > 0) << 3);
    mask16[(size_t)b * (V_ / 4) + i4] = (unsigned short)(n0 | (n1 << 4) | (n2 << 8) | (n3 << 12));

    unsigned p01 = ((unsigned)(ya.x > 0) + (ya.y > 0) + (ya.z > 0) + (ya.w > 0))
                 | (((unsigned)(yb.x > 0) + (yb.y > 0) + (yb.z > 0) + (yb.w > 0)) << 16);
    unsigned p23 = ((unsigned)(yc.x > 0) + (yc.y > 0) + (yc.z > 0) + (yc.w > 0))
                 | (((unsigned)(yd.x > 0) + (yd.y > 0) + (yd.z > 0) + (yd.w > 0)) << 16);
    #pragma unroll
    for (int o = 1; o < 64; o <<= 1) {
        p01 += __shfl_xor(p01, o, 64);
        p23 += __shfl_xor(p23, o, 64);
    }
    if (lane == 0) { wc[wave][0] = p01; wc[wave][1] = p23; }

    // ---- proba -> wbits + LDS hist1 ----
    const float* p0 = proba + (size_t)(b * C_) * V_;
    float4 qa = ((const float4*)p0)[i4];
    float4 qb = ((const float4*)(p0 + V_))[i4];
    float4 qc = ((const float4*)(p0 + 2 * V_))[i4];
    float4 qd = ((const float4*)(p0 + 3 * V_))[i4];
    uint4 wb;
    wb.x = __float_as_uint(((qa.x * qb.x) * qc.x) * qd.x);
    wb.y = __float_as_uint(((qa.y * qb.y) * qc.y) * qd.y);
    wb.z = __float_as_uint(((qa.z * qb.z) * qc.z) * qd.z);
    wb.w = __float_as_uint(((qa.w * qb.w) * qc.w) * qd.w);
    ((uint4*)wbits)[(size_t)b * (V_ / 4) + i4] = wb;
    atomicAdd(&lh[wb.x >> 24], 1u);
    atomicAdd(&lh[wb.y >> 24], 1u);
    atomicAdd(&lh[wb.z >> 24], 1u);
    atomicAdd(&lh[wb.w >> 24], 1u);
    __syncthreads();

    hist1p[(blk << 8) | tid] = (unsigned short)lh[tid];
    if (tid == 0) {
        unsigned q01 = wc[0][0] + wc[1][0] + wc[2][0] + wc[3][0];
        unsigned q23 = wc[0][1] + wc[1][1] + wc[2][1] + wc[3][1];
        unsigned* o4 = cntp + (blk << 2);
        o4[0] = q01 & 0xFFFFu; o4[1] = q01 >> 16;
        o4[2] = q23 & 0xFFFFu; o4[3] = q23 >> 16;
    }

    // ---- decoupled last-block: thresh0 + cnt reduce ----
    __threadfence();
    if (tid == 0) lastFlag = (atomicAdd(ctr, 1u) == 1023u) ? 1u : 0u;
    __syncthreads();
    if (lastFlag) {
        __threadfence();
        int bb = wave;   // wave w handles batch w
        unsigned g0 = 0, g1 = 0, g2 = 0, g3 = 0;
        for (int c = 0; c < 256; ++c) {
            ull v = ((const ull*)hist1p)[((((bb << 8) | c) << 6)) | lane];
            g0 += (unsigned)(v & 0xFFFFu);
            g1 += (unsigned)((v >> 16) & 0xFFFFu);
            g2 += (unsigned)((v >> 32) & 0xFFFFu);
            g3 += (unsigned)((v >> 48) & 0xFFFFu);
        }
        scan_thresh(g0, g1, g2, g3, 0u, 0u, lane, ctrl1 + bb * 2);

        if (wave == 0) {
            unsigned s0 = 0, s1 = 0, s2 = 0, s3 = 0;
            #pragma unroll
            for (int r = 0; r < 16; ++r) {
                uint4 p = ((const uint4*)cntp)[(r << 6) | lane];
                s0 += p.x; s1 += p.y; s2 += p.z; s3 += p.w;
            }
            #pragma unroll
            for (int o = 1; o < 64; o <<= 1) {
                s0 += __shfl_xor(s0, o, 64);
                s1 += __shfl_xor(s1, o, 64);
                s2 += __shfl_xor(s2, o, 64);
                s3 += __shfl_xor(s3, o, 64);
            }
            if (lane == 0) {
                cnt[0] = (float)s0; cnt[1] = (float)s1;
                cnt[2] = (float)s2; cnt[3] = (float)s3;
            }
        }
    }
}

// level-2 histogram; LAST block folds in thresh1.
__global__ __launch_bounds__(256) void k_hist2(const unsigned* __restrict__ wbits,
                                               const unsigned* __restrict__ ctrl1,
                                               unsigned* __restrict__ hist2,
                                               unsigned* __restrict__ ctrl2,
                                               unsigned* __restrict__ ctr) {
    __shared__ unsigned lh[256];
    __shared__ unsigned lastFlag;
    int tid = threadIdx.x;
    int wave = tid >> 6, lane = tid & 63;
    lh[tid] = 0u;
    __syncthreads();
    int b = blockIdx.x >> 8;
    int base = (blockIdx.x & 255) << 10;
    unsigned T1 = ctrl1[b * 2];
    for (int it = 0; it < 4; ++it) {
        int v = base + tid + (it << 8);
        unsigned bits = wbits[(size_t)b * V_ + v];
        if ((bits >> 24) == T1) atomicAdd(&lh[(bits >> 16) & 0xFF], 1u);
    }
    __syncthreads();
    if (lh[tid]) atomicAdd(&hist2[b * 256 + tid], lh[tid]);

    __threadfence();
    if (tid == 0) lastFlag = (atomicAdd(ctr, 1u) == 1023u) ? 1u : 0u;
    __syncthreads();
    if (lastFlag) {
        __threadfence();
        int bb = wave;
        uint4 g = ((const uint4*)hist2)[(bb << 6) | lane];
        scan_thresh(g.x, g.y, g.z, g.w, ctrl1[bb * 2 + 1], ctrl1[bb * 2], lane, ctrl2 + bb * 2);
    }
}

// bitonic compare-exchange steps (descending sort, 512 virtual lanes,
// 8 keys/lane, p = (lane<<3)|r). Fully static-unrolled (rule #20).
#define XSTEP(kk_, k_, j_) { \
    _Pragma("unroll") \
    for (int r = 0; r < 8; ++r) { \
        ull o = __shfl_xor(kk_[r], (j_) >> 3, 64); \
        int p = (lane << 3) | r; \
        bool keepmax = (((p & (k_)) == 0) == ((p & (j_)) == 0)); \
        kk_[r] = (keepmax == (kk_[r] > o)) ? kk_[r] : o; \
    } }
#define LSTEP(kk_, k_, j_) { \
    _Pragma("unroll") \
    for (int r = 0; r < 8; ++r) { \
        if (!(r & (j_))) { \
            int p = (lane << 3) | r; \
            bool up = ((p & (k_)) == 0); \
            ull a = kk_[r], c = kk_[r | (j_)]; \
            ull mx = a > c ? a : c, mn = a > c ? c : a; \
            kk_[r] = up ? mx : mn; \
            kk_[r | (j_)] = up ? mn : mx; \
        } \
    } }

// collect candidates; LAST block folds in the exact top-K select
// (wave w = batch w; 512-wide register bitonic, exact lax.top_k order).
__global__ __launch_bounds__(256) void k_collect(const unsigned* __restrict__ wbits,
                                                 const unsigned* __restrict__ ctrl2,
                                                 unsigned* __restrict__ ccount,
                                                 unsigned* __restrict__ cbits,
                                                 unsigned* __restrict__ cidx,
                                                 unsigned* __restrict__ idxout,
                                                 unsigned* __restrict__ ctr) {
    __shared__ unsigned lastFlag;
    int b = blockIdx.x >> 8;
    int base = (blockIdx.x & 255) << 10;
    int tid = threadIdx.x;
    int wave = tid >> 6, lane = tid & 63;
    unsigned P16 = ctrl2[b * 2];
    for (int it = 0; it < 4; ++it) {
        int v = base + tid + (it << 8);
        unsigned bits = wbits[(size_t)b * V_ + v];
        if ((bits >> 16) >= P16) {
            unsigned pos = atomicAdd(&ccount[b], 1u);
            if (pos < CAP2) { cbits[b * CAP2 + pos] = bits; cidx[b * CAP2 + pos] = (unsigned)v; }
        }
    }

    __threadfence();
    if (tid == 0) lastFlag = (atomicAdd(ctr, 1u) == 1023u) ? 1u : 0u;
    __syncthreads();
    if (lastFlag) {
        __threadfence();
        int bb = wave;
        unsigned nc = ccount[bb];
        int n = (int)(nc < CAP2 ? nc : CAP2);
        if (n <= 512) {
            ull kk[8];
            #pragma unroll
            for (int r = 0; r < 8; ++r) {
                int p = (lane << 3) | r;
                kk[r] = (p < n) ? (((ull)cbits[bb * CAP2 + p] << 32) | (unsigned)(~cidx[bb * CAP2 + p])) : 0ull;
            }
            LSTEP(kk, 2, 1)
            LSTEP(kk, 4, 2) LSTEP(kk, 4, 1)
            LSTEP(kk, 8, 4) LSTEP(kk, 8, 2) LSTEP(kk, 8, 1)
            XSTEP(kk, 16, 8) LSTEP(kk, 16, 4) LSTEP(kk, 16, 2) LSTEP(kk, 16, 1)
            XSTEP(kk, 32, 16) XSTEP(kk, 32, 8) LSTEP(kk, 32, 4) LSTEP(kk, 32, 2) LSTEP(kk, 32, 1)
            XSTEP(kk, 64, 32) XSTEP(kk, 64, 16) XSTEP(kk, 64, 8) LSTEP(kk, 64, 4) LSTEP(kk, 64, 2) LSTEP(kk, 64, 1)
            XSTEP(kk, 128, 64) XSTEP(kk, 128, 32) XSTEP(kk, 128, 16) XSTEP(kk, 128, 8) LSTEP(kk, 128, 4) LSTEP(kk, 128, 2) LSTEP(kk, 128, 1)
            XSTEP(kk, 256, 128) XSTEP(kk, 256, 64) XSTEP(kk, 256, 32) XSTEP(kk, 256, 16) XSTEP(kk, 256, 8) LSTEP(kk, 256, 4) LSTEP(kk, 256, 2) LSTEP(kk, 256, 1)
            XSTEP(kk, 512, 256) XSTEP(kk, 512, 128) XSTEP(kk, 512, 64) XSTEP(kk, 512, 32) XSTEP(kk, 512, 16) XSTEP(kk, 512, 8) LSTEP(kk, 512, 4) LSTEP(kk, 512, 2) LSTEP(kk, 512, 1)
            #pragma unroll
            for (int r = 0; r < 8; ++r) {
                int p = (lane << 3) | r;
                if (p < K_) idxout[bb * K_ + p] = ~(unsigned)(kk[r] & 0xFFFFFFFFull);
            }
        } else {
            // rare fallback: iterative selection (n>512 not expected: n ~ K + one 16-bit bin)
            for (int k = 0; k < K_; ++k) {
                ull m = 0ull; int ms = -1;
                for (int i = lane; i < n; i += 64) {
                    ull key = ((ull)cbits[bb * CAP2 + i] << 32) | (unsigned)(~cidx[bb * CAP2 + i]);
                    if (key > m) { m = key; ms = i; }
                }
                ull lm_ = m;
                #pragma unroll
                for (int o = 1; o < 64; o <<= 1) {
                    ull other = __shfl_xor(m, o, 64);
                    if (other > m) m = other;
                }
                if (ms >= 0 && lm_ == m) { cbits[bb * CAP2 + ms] = 0u; cidx[bb * CAP2 + ms] = 0xFFFFFFFFu; }
                if (lane == 0) idxout[bb * K_ + k] = ~(unsigned)(m & 0xFFFFFFFFull);
            }
        }
    }
}

// class_sum: pure stream; masks from LDS; atomics spread over 8 cs replicas.
__global__ __launch_bounds__(256) void k_class_sum(const float* __restrict__ emb,
                                                   const unsigned short* __restrict__ mask16,
                                                   float* __restrict__ cs2) {
    __shared__ unsigned short smask[2048];
    int blk = blockIdx.x;
    int tid = threadIdx.x;
    int wave = tid >> 6, lane = tid & 63;
    int b = blk >> 9;
    int rem = blk & 511;
    int fgrp = rem >> 5;
    int s = rem & 31;
    int f = (fgrp << 2) | wave;

    ((uint4*)smask)[tid] = ((const uint4*)(mask16 + (size_t)b * (V_ / 4) + (s << 11)))[tid];
    __syncthreads();

    const float4* ep = (const float4*)emb + ((size_t)((b << 6) | f)) * (V_ / 4) + (s << 11);

    float a0 = 0.f, a1 = 0.f, a2 = 0.f, a3 = 0.f;
    #pragma unroll
    for (int o = 0; o < 4; ++o) {
        float4 e[8];
        unsigned mm[8];
        #pragma unroll
        for (int i = 0; i < 8; ++i) e[i] = ep[(((o << 3) | i) << 6) | lane];
        #pragma unroll
        for (int i = 0; i < 8; ++i) mm[i] = smask[(((o << 3) | i) << 6) | lane];
        #pragma unroll
        for (int i = 0; i < 8; ++i) {
            unsigned m = mm[i];
            float4 ev = e[i];
            a0 += ( m        & 1u ? ev.x : 0.f) + ((m >>  4) & 1u ? ev.y : 0.f)
                + ((m >>  8) & 1u ? ev.z : 0.f) + ((m >> 12) & 1u ? ev.w : 0.f);
            a1 += ((m >>  1) & 1u ? ev.x : 0.f) + ((m >>  5) & 1u ? ev.y : 0.f)
                + ((m >>  9) & 1u ? ev.z : 0.f) + ((m >> 13) & 1u ? ev.w : 0.f);
            a2 += ((m >>  2) & 1u ? ev.x : 0.f) + ((m >>  6) & 1u ? ev.y : 0.f)
                + ((m >> 10) & 1u ? ev.z : 0.f) + ((m >> 14) & 1u ? ev.w : 0.f);
            a3 += ((m >>  3) & 1u ? ev.x : 0.f) + ((m >>  7) & 1u ? ev.y : 0.f)
                + ((m >> 11) & 1u ? ev.z : 0.f) + ((m >> 15) & 1u ? ev.w : 0.f);
        }
    }
    #pragma unroll
    for (int o = 1; o < 64; o <<= 1) {
        a0 += __shfl_xor(a0, o, 64);
        a1 += __shfl_xor(a1, o, 64);
        a2 += __shfl_xor(a2, o, 64);
        a3 += __shfl_xor(a3, o, 64);
    }
    float av = (lane == 0) ? a0 : (lane == 1) ? a1 : (lane == 2) ? a2 : a3;
    if (lane < 4) atomicAdd(&cs2[((blk & 7) << 8) | (lane << 6) | f], av);
}

// final: one wave (64 lanes = F) per (b,k); sums the 8 cs replicas inline.
__global__ __launch_bounds__(64) void k_final(const float* __restrict__ emb,
                                              const int* __restrict__ y,
                                              const float* __restrict__ avg,
                                              const float* __restrict__ cs2,
                                              const float* __restrict__ cnt,
                                              const unsigned* __restrict__ idxout,
                                              float* __restrict__ out) {
    int blk = blockIdx.x;
    int b = blk / K_;
    int k = blk % K_;
    int lane = threadIdx.x;
    unsigned v = idxout[b * K_ + k];

    float e = emb[((size_t)(b * F_ + lane)) * V_ + v];

    int y0v = y[((size_t)(b * C_ + 0)) * V_ + v];
    int y1v = y[((size_t)(b * C_ + 1)) * V_ + v];
    int y2v = y[((size_t)(b * C_ + 2)) * V_ + v];
    int y3v = y[((size_t)(b * C_ + 3)) * V_ + v];
    int cm = (y0v > 0) ? 0 : ((y1v > 0) ? 1 : ((y2v > 0) ? 2 : ((y3v > 0) ? 3 : 0)));
    float sel = (cm == 0) ? 1.f : 0.f;

    float t = e / TAU_;
    float ssum = 0.f;
    #pragma unroll
    for (int c = 1; c < 4; ++c) {
        float cc = cnt[c];
        float csum = 0.f;
        #pragma unroll
        for (int rep = 0; rep < 8; ++rep) csum += cs2[(rep << 8) | (c << 6) | lane];
        float mean = csum / fmaxf(cc, 1.f);
        float av = avg[c * F_ + lane];
        float nar = (cc > 0.f) ? (av * (1.f - THETA) + mean * THETA) : av;
        ssum += expf(t * nar);
    }
    float term = -logf(ssum);
    #pragma unroll
    for (int o = 32; o > 0; o >>= 1) term += __shfl_down(term, o, 64);
    if (lane == 0) out[b * K_ + k] = term * sel;
}

extern "C" void kernel_launch(void* const* d_in, const int* in_sizes, int n_in,
                              void* d_out, int out_size, void* d_ws, size_t ws_size,
                              hipStream_t stream) {
    const float* proba = (const float*)d_in[0];
    const int* y = (const int*)d_in[1];
    const float* emb = (const float*)d_in[2];
    const float* avg = (const float*)d_in[3];
    float* out = (float*)d_out;

    char* ws = (char*)d_ws;
    float* cs2 = (float*)(ws + 0);
    float* cnt = (float*)(ws + 8192);
    unsigned* ctrl1 = (unsigned*)(ws + 8208);
    unsigned* ctrl2 = (unsigned*)(ws + 8240);
    unsigned* ccount = (unsigned*)(ws + 8272);
    unsigned* idxout = (unsigned*)(ws + 8320);
    unsigned* hist2 = (unsigned*)(ws + 10240);
    unsigned* ctrs = (unsigned*)(ws + 14336);
    unsigned* cbits = (unsigned*)(ws + 16384);
    unsigned* cidx = (unsigned*)(ws + 81920);
    unsigned* cntp = (unsigned*)(ws + 147456);
    unsigned short* hist1p = (unsigned short*)(ws + 163840);
    unsigned short* mask16 = (unsigned short*)(ws + 688128);
    unsigned* wbits = (unsigned*)(ws + 1212416);

    hipMemsetAsync(ctrs, 0, 12, stream);
    k_prep<<<B_ * 256, 256, 0, stream>>>(y, proba, mask16, cntp, hist1p, wbits,
                                         cs2, hist2, ccount, ctrl1, cnt, ctrs + 0);
    k_hist2<<<B_ * 256, 256, 0, stream>>>(wbits, ctrl1, hist2, ctrl2, ctrs + 1);
    k_collect<<<B_ * 256, 256, 0, stream>>>(wbits, ctrl2, ccount, cbits, cidx, idxout, ctrs + 2);
    k_class_sum<<<2048, 256, 0, stream>>>(emb, mask16, cs2);
    k_final<<<B_ * K_, 64, 0, stream>>>(emb, y, avg, cs2, cnt, idxout, out);
}

// Round 11
// 135.807 us; speedup vs baseline: 3.8272x; 2.3653x over previous
//
#include <hip/hip_runtime.h>

#define B_ 4
#define C_ 4
#define V_ 262144
#define F_ 64
#define K_ 100
#define THETA 0.9f
#define TAU_ 0.1f
#define CAP2 4096

typedef unsigned long long ull;

// ---------------- workspace layout (bytes) ----------------
// cs2    : 0       .. 8192     (8 replicas x C x F f32)
// cnt    : 8192    .. 8208     (C f32)
// ctrl1  : 8208    .. 8240     (B*2 u32: T1, n_above)
// ctrl2  : 8240    .. 8272     (B*2 u32: P16, n_above2)
// ccount : 8272    .. 8288     (B u32)
// idxout : 8320    .. 9920     (B*K u32)
// hist2  : 10240   .. 14336    (B*256 u32)
// cbits  : 16384   .. 81920    (B*CAP2 u32)
// cidx   : 81920   .. 147456   (B*CAP2 u32)
// cntp   : 147456  .. 163840   (1024*4 u32 per-block count partials)
// hist1p : 163840  .. 688128   (1024*256 u16 per-block hist1 partials)
// mask16 : 688128  .. 1212416  (B*V/4 u16 packed 4-bit class masks)
// wbits  : 1212416 .. 5406720  (B*V u32 product-weight float bits)

// Fused: init + y->mask16/count-partials + proba->wbits/hist1-partials.
__global__ __launch_bounds__(256) void k_prep(const int* __restrict__ y,
                                              const float* __restrict__ proba,
                                              unsigned short* __restrict__ mask16,
                                              unsigned* __restrict__ cntp,
                                              unsigned short* __restrict__ hist1p,
                                              unsigned* __restrict__ wbits,
                                              float* __restrict__ cs2,
                                              unsigned* __restrict__ hist2,
                                              unsigned* __restrict__ ccount) {
    __shared__ unsigned lh[256];
    __shared__ unsigned wc[4][2];
    int blk = blockIdx.x;
    int tid = threadIdx.x;
    int wave = tid >> 6, lane = tid & 63;
    int b = blk >> 8;
    int i4 = ((blk & 255) << 8) | tid;   // float4-group in [0, V/4)

    lh[tid] = 0u;
    // folded init (arrays only consumed by LATER kernels -> no race)
    if (blk < 8) cs2[(blk << 8) | tid] = 0.f;
    else if (blk < 12) hist2[((blk - 8) << 8) | tid] = 0u;
    else if (blk == 12 && tid < 4) ccount[tid] = 0u;
    __syncthreads();

    // ---- y -> packed masks + per-block counts ----
    const int4* y0 = (const int4*)(y + ((size_t)(b * C_ + 0)) * V_);
    const int4* y1 = (const int4*)(y + ((size_t)(b * C_ + 1)) * V_);
    const int4* y2 = (const int4*)(y + ((size_t)(b * C_ + 2)) * V_);
    const int4* y3 = (const int4*)(y + ((size_t)(b * C_ + 3)) * V_);
    int4 ya = y0[i4], yb = y1[i4], yc = y2[i4], yd = y3[i4];

    unsigned n0 = (unsigned)(ya.x > 0) | ((unsigned)(yb.x > 0) << 1) | ((unsigned)(yc.x > 0) << 2) | ((unsigned)(yd.x > 0) << 3);
    unsigned n1 = (unsigned)(ya.y > 0) | ((unsigned)(yb.y > 0) << 1) | ((unsigned)(yc.y > 0) << 2) | ((unsigned)(yd.y > 0) << 3);
    unsigned n2 = (unsigned)(ya.z > 0) | ((unsigned)(yb.z > 0) << 1) | ((unsigned)(yc.z > 0) << 2) | ((unsigned)(yd.z > 0) << 3);
    unsigned n3 = (unsigned)(ya.w > 0) | ((unsigned)(yb.w > 0) << 1) | ((unsigned)(yc.w > 0) << 2) | ((unsigned)(yd.w > 0) << 3);
    mask16[(size_t)b * (V_ / 4) + i4] = (unsigned short)(n0 | (n1 << 4) | (n2 << 8) | (n3 << 12));

    unsigned p01 = ((unsigned)(ya.x > 0) + (ya.y > 0) + (ya.z > 0) + (ya.w > 0))
                 | (((unsigned)(yb.x > 0) + (yb.y > 0) + (yb.z > 0) + (yb.w > 0)) << 16);
    unsigned p23 = ((unsigned)(yc.x > 0) + (yc.y > 0) + (yc.z > 0) + (yc.w > 0))
                 | (((unsigned)(yd.x > 0) + (yd.y > 0) + (yd.z > 0) + (yd.w > 0)) << 16);
    #pragma unroll
    for (int o = 1; o < 64; o <<= 1) {
        p01 += __shfl_xor(p01, o, 64);
        p23 += __shfl_xor(p23, o, 64);
    }
    if (lane == 0) { wc[wave][0] = p01; wc[wave][1] = p23; }

    // ---- proba -> wbits + LDS hist1 ----
    const float* p0 = proba + (size_t)(b * C_) * V_;
    float4 qa = ((const float4*)p0)[i4];
    float4 qb = ((const float4*)(p0 + V_))[i4];
    float4 qc = ((const float4*)(p0 + 2 * V_))[i4];
    float4 qd = ((const float4*)(p0 + 3 * V_))[i4];
    uint4 wb;
    wb.x = __float_as_uint(((qa.x * qb.x) * qc.x) * qd.x);
    wb.y = __float_as_uint(((qa.y * qb.y) * qc.y) * qd.y);
    wb.z = __float_as_uint(((qa.z * qb.z) * qc.z) * qd.z);
    wb.w = __float_as_uint(((qa.w * qb.w) * qc.w) * qd.w);
    ((uint4*)wbits)[(size_t)b * (V_ / 4) + i4] = wb;
    atomicAdd(&lh[wb.x >> 24], 1u);
    atomicAdd(&lh[wb.y >> 24], 1u);
    atomicAdd(&lh[wb.z >> 24], 1u);
    atomicAdd(&lh[wb.w >> 24], 1u);
    __syncthreads();

    hist1p[(blk << 8) | tid] = (unsigned short)lh[tid];
    if (tid == 0) {
        unsigned q01 = wc[0][0] + wc[1][0] + wc[2][0] + wc[3][0];
        unsigned q23 = wc[0][1] + wc[1][1] + wc[2][1] + wc[3][1];
        unsigned* o4 = cntp + (blk << 2);
        o4[0] = q01 & 0xFFFFu; o4[1] = q01 >> 16;
        o4[2] = q23 & 0xFFFFu; o4[3] = q23 >> 16;
    }
}

// reduce hist1 partials + scan -> T1; block 0 also reduces cnt partials.
__global__ __launch_bounds__(256) void k_thresh0(const unsigned short* __restrict__ hist1p,
                                                 const unsigned* __restrict__ cntp,
                                                 unsigned* __restrict__ ctrl1,
                                                 float* __restrict__ cnt) {
    __shared__ unsigned bins[256];
    int b = blockIdx.x;
    int tid = threadIdx.x;
    int wave = tid >> 6, lane = tid & 63;
    unsigned s = 0;
    for (int c = 0; c < 256; ++c)
        s += hist1p[(((b << 8) | c) << 8) | tid];
    bins[tid] = s;
    __syncthreads();
    if (wave == 0) {
        int binbase = 255 - 4 * lane;
        unsigned c0 = bins[binbase], c1 = bins[binbase - 1], c2 = bins[binbase - 2], c3 = bins[binbase - 3];
        unsigned cnt4 = c0 + c1 + c2 + c3;
        unsigned pref = cnt4;
        #pragma unroll
        for (int o = 1; o < 64; o <<= 1) {
            unsigned u = __shfl_up(pref, o, 64);
            if (lane >= o) pref += u;
        }
        unsigned above = pref - cnt4;
        unsigned t = above;
        int found = -1; unsigned nab = 0;
        if (t + c0 >= K_)                { found = binbase;     nab = t; }
        else if (t + c0 + c1 >= K_)      { found = binbase - 1; nab = t + c0; }
        else if (t + c0 + c1 + c2 >= K_) { found = binbase - 2; nab = t + c0 + c1; }
        else if (t + cnt4 >= K_)         { found = binbase - 3; nab = t + c0 + c1 + c2; }
        if (found >= 0 && above < K_) {
            ctrl1[b * 2] = (unsigned)found;
            ctrl1[b * 2 + 1] = nab;
        }
    } else if (wave == 1 && b == 0) {
        unsigned s0 = 0, s1 = 0, s2 = 0, s3 = 0;
        #pragma unroll
        for (int r = 0; r < 16; ++r) {
            uint4 p = ((const uint4*)cntp)[(r << 6) | lane];
            s0 += p.x; s1 += p.y; s2 += p.z; s3 += p.w;
        }
        #pragma unroll
        for (int o = 1; o < 64; o <<= 1) {
            s0 += __shfl_xor(s0, o, 64);
            s1 += __shfl_xor(s1, o, 64);
            s2 += __shfl_xor(s2, o, 64);
            s3 += __shfl_xor(s3, o, 64);
        }
        if (lane == 0) {
            cnt[0] = (float)s0; cnt[1] = (float)s1;
            cnt[2] = (float)s2; cnt[3] = (float)s3;
        }
    }
}

// level-2 histogram: next 8 bits, only for elements in bin T1 (reads wbits)
__global__ __launch_bounds__(256) void k_hist2(const unsigned* __restrict__ wbits,
                                               const unsigned* __restrict__ ctrl1,
                                               unsigned* __restrict__ hist2) {
    __shared__ unsigned lh[256];
    int tid = threadIdx.x;
    lh[tid] = 0u;
    __syncthreads();
    int b = blockIdx.x >> 8;
    int base = (blockIdx.x & 255) << 10;
    unsigned T1 = ctrl1[b * 2];
    for (int it = 0; it < 4; ++it) {
        int v = base + tid + (it << 8);
        unsigned bits = wbits[(size_t)b * V_ + v];
        if ((bits >> 24) == T1) atomicAdd(&lh[(bits >> 16) & 0xFF], 1u);
    }
    __syncthreads();
    if (lh[tid]) atomicAdd(&hist2[b * 256 + tid], lh[tid]);  // sparse, shallow chains
}

// second-level threshold: P16 = (T1<<8)|T2
__global__ __launch_bounds__(256) void k_thresh1(const unsigned* __restrict__ hist,
                                                 const unsigned* __restrict__ ctrl_in,
                                                 unsigned* __restrict__ ctrl_out) {
    int b = threadIdx.x >> 6;
    int lane = threadIdx.x & 63;
    const unsigned* h = hist + b * 256;
    unsigned base = ctrl_in[b * 2 + 1];
    int binbase = 255 - 4 * lane;
    unsigned c0 = h[binbase], c1 = h[binbase - 1], c2 = h[binbase - 2], c3 = h[binbase - 3];
    unsigned cnt4 = c0 + c1 + c2 + c3;
    unsigned pref = cnt4;
    #pragma unroll
    for (int o = 1; o < 64; o <<= 1) {
        unsigned u = __shfl_up(pref, o, 64);
        if (lane >= o) pref += u;
    }
    unsigned above = base + pref - cnt4;
    unsigned t = above;
    int found = -1; unsigned nab = 0;
    if (t + c0 >= K_)                { found = binbase;     nab = t; }
    else if (t + c0 + c1 >= K_)      { found = binbase - 1; nab = t + c0; }
    else if (t + c0 + c1 + c2 >= K_) { found = binbase - 2; nab = t + c0 + c1; }
    else if (t + cnt4 >= K_)         { found = binbase - 3; nab = t + c0 + c1 + c2; }
    if (found >= 0 && above < K_) {
        ctrl_out[b * 2] = (ctrl_in[b * 2] << 8) | (unsigned)found;
        ctrl_out[b * 2 + 1] = nab;
    }
}

// collect all candidates with (bits>>16) >= P16
__global__ __launch_bounds__(256) void k_collect(const unsigned* __restrict__ wbits,
                                                 const unsigned* __restrict__ ctrl2,
                                                 unsigned* __restrict__ ccount,
                                                 unsigned* __restrict__ cbits,
                                                 unsigned* __restrict__ cidx) {
    int b = blockIdx.x >> 8;
    int base = (blockIdx.x & 255) << 10;
    int tid = threadIdx.x;
    unsigned P16 = ctrl2[b * 2];
    for (int it = 0; it < 4; ++it) {
        int v = base + tid + (it << 8);
        unsigned bits = wbits[(size_t)b * V_ + v];
        if ((bits >> 16) >= P16) {
            unsigned pos = atomicAdd(&ccount[b], 1u);
            if (pos < CAP2) { cbits[b * CAP2 + pos] = bits; cidx[b * CAP2 + pos] = (unsigned)v; }
        }
    }
}

// exact top-K: one wave per b, lane-private LDS regions, zero barriers.
__global__ __launch_bounds__(64) void k_select(const unsigned* __restrict__ ccount,
                                               const unsigned* __restrict__ cbits,
                                               const unsigned* __restrict__ cidx,
                                               unsigned* __restrict__ idxout) {
    __shared__ ull keys[CAP2];
    int b = blockIdx.x;
    int lane = threadIdx.x;
    unsigned nc = ccount[b];
    int n = (int)(nc < CAP2 ? nc : CAP2);
    for (int i = lane; i < n; i += 64)
        keys[i] = ((ull)cbits[b * CAP2 + i] << 32) | (unsigned)(~cidx[b * CAP2 + i]);
    for (int k = 0; k < K_; ++k) {
        ull m = 0ull; int mslot = -1;
        for (int i = lane; i < n; i += 64) {
            ull key = keys[i];
            if (key > m) { m = key; mslot = i; }
        }
        ull lm = m;
        #pragma unroll
        for (int o = 1; o < 64; o <<= 1) {
            ull other = __shfl_xor(m, o, 64);
            if (other > m) m = other;
        }
        if (mslot >= 0 && lm == m) keys[mslot] = 0ull;
        if (lane == 0) idxout[b * K_ + k] = ~(unsigned)(m & 0xFFFFFFFFull);
    }
}

// class_sum: ONE contiguous 256KB stream per block (page-locality theory:
// 1024 long streams instead of 8192 short ones). Masks staged to 32KB LDS.
// All 256 threads accumulate the SAME (b,f) row; block reduce at end.
__global__ __launch_bounds__(256) void k_class_sum(const float* __restrict__ emb,
                                                   const unsigned short* __restrict__ mask16,
                                                   float* __restrict__ cs2) {
    __shared__ unsigned short smask[16384];   // 32 KB: masks for 65536 v
    __shared__ float wsum[4][4];
    int blk = blockIdx.x;        // 1024 = b(2b) | f(6b) | s(2b)
    int tid = threadIdx.x;
    int wave = tid >> 6, lane = tid & 63;
    int s = blk & 3;
    int f = (blk >> 2) & 63;
    int b = blk >> 8;

    // stage masks: 2048 uint4, 8 per thread, coalesced
    {
        const uint4* msrc = (const uint4*)(mask16 + (size_t)b * (V_ / 4) + (s << 14));
        uint4* mdst = (uint4*)smask;
        #pragma unroll
        for (int i = 0; i < 8; ++i) mdst[(i << 8) | tid] = msrc[(i << 8) | tid];
    }
    __syncthreads();

    // one contiguous 256 KB stream: 16384 float4, thread does 64 (8 batches of 8)
    const float4* ep = (const float4*)emb + ((size_t)((b << 6) | f)) * (V_ / 4) + ((size_t)s << 14);

    float a0 = 0.f, a1 = 0.f, a2 = 0.f, a3 = 0.f;
    for (int o = 0; o < 8; ++o) {
        float4 e[8];
        unsigned mm[8];
        #pragma unroll
        for (int i = 0; i < 8; ++i) e[i] = ep[(((o << 3) | i) << 8) | tid];
        #pragma unroll
        for (int i = 0; i < 8; ++i) mm[i] = smask[(((o << 3) | i) << 8) | tid];
        #pragma unroll
        for (int i = 0; i < 8; ++i) {
            unsigned m = mm[i];
            float4 ev = e[i];
            a0 += ( m        & 1u ? ev.x : 0.f) + ((m >>  4) & 1u ? ev.y : 0.f)
                + ((m >>  8) & 1u ? ev.z : 0.f) + ((m >> 12) & 1u ? ev.w : 0.f);
            a1 += ((m >>  1) & 1u ? ev.x : 0.f) + ((m >>  5) & 1u ? ev.y : 0.f)
                + ((m >>  9) & 1u ? ev.z : 0.f) + ((m >> 13) & 1u ? ev.w : 0.f);
            a2 += ((m >>  2) & 1u ? ev.x : 0.f) + ((m >>  6) & 1u ? ev.y : 0.f)
                + ((m >> 10) & 1u ? ev.z : 0.f) + ((m >> 14) & 1u ? ev.w : 0.f);
            a3 += ((m >>  3) & 1u ? ev.x : 0.f) + ((m >>  7) & 1u ? ev.y : 0.f)
                + ((m >> 11) & 1u ? ev.z : 0.f) + ((m >> 15) & 1u ? ev.w : 0.f);
        }
    }
    #pragma unroll
    for (int o = 1; o < 64; o <<= 1) {
        a0 += __shfl_xor(a0, o, 64);
        a1 += __shfl_xor(a1, o, 64);
        a2 += __shfl_xor(a2, o, 64);
        a3 += __shfl_xor(a3, o, 64);
    }
    if (lane == 0) { wsum[wave][0] = a0; wsum[wave][1] = a1; wsum[wave][2] = a2; wsum[wave][3] = a3; }
    __syncthreads();
    if (tid < 4) {
        float v = wsum[0][tid] + wsum[1][tid] + wsum[2][tid] + wsum[3][tid];
        atomicAdd(&cs2[((blk & 7) << 8) | (tid << 6) | f], v);   // <=4-deep chains
    }
}

// final: one wave (64 lanes = F) per (b,k); sums the 8 cs replicas inline.
__global__ __launch_bounds__(64) void k_final(const float* __restrict__ emb,
                                              const int* __restrict__ y,
                                              const float* __restrict__ avg,
                                              const float* __restrict__ cs2,
                                              const float* __restrict__ cnt,
                                              const unsigned* __restrict__ idxout,
                                              float* __restrict__ out) {
    int blk = blockIdx.x;
    int b = blk / K_;
    int k = blk % K_;
    int lane = threadIdx.x;
    unsigned v = idxout[b * K_ + k];

    float e = emb[((size_t)(b * F_ + lane)) * V_ + v];

    int y0v = y[((size_t)(b * C_ + 0)) * V_ + v];
    int y1v = y[((size_t)(b * C_ + 1)) * V_ + v];
    int y2v = y[((size_t)(b * C_ + 2)) * V_ + v];
    int y3v = y[((size_t)(b * C_ + 3)) * V_ + v];
    int cm = (y0v > 0) ? 0 : ((y1v > 0) ? 1 : ((y2v > 0) ? 2 : ((y3v > 0) ? 3 : 0)));
    float sel = (cm == 0) ? 1.f : 0.f;

    float t = e / TAU_;
    float ssum = 0.f;
    #pragma unroll
    for (int c = 1; c < 4; ++c) {
        float cc = cnt[c];
        float csum = 0.f;
        #pragma unroll
        for (int rep = 0; rep < 8; ++rep) csum += cs2[(rep << 8) | (c << 6) | lane];
        float mean = csum / fmaxf(cc, 1.f);
        float av = avg[c * F_ + lane];
        float nar = (cc > 0.f) ? (av * (1.f - THETA) + mean * THETA) : av;
        ssum += expf(t * nar);
    }
    float term = -logf(ssum);
    #pragma unroll
    for (int o = 32; o > 0; o >>= 1) term += __shfl_down(term, o, 64);
    if (lane == 0) out[b * K_ + k] = term * sel;
}

extern "C" void kernel_launch(void* const* d_in, const int* in_sizes, int n_in,
                              void* d_out, int out_size, void* d_ws, size_t ws_size,
                              hipStream_t stream) {
    const float* proba = (const float*)d_in[0];
    const int* y = (const int*)d_in[1];
    const float* emb = (const float*)d_in[2];
    const float* avg = (const float*)d_in[3];
    float* out = (float*)d_out;

    char* ws = (char*)d_ws;
    float* cs2 = (float*)(ws + 0);
    float* cnt = (float*)(ws + 8192);
    unsigned* ctrl1 = (unsigned*)(ws + 8208);
    unsigned* ctrl2 = (unsigned*)(ws + 8240);
    unsigned* ccount = (unsigned*)(ws + 8272);
    unsigned* idxout = (unsigned*)(ws + 8320);
    unsigned* hist2 = (unsigned*)(ws + 10240);
    unsigned* cbits = (unsigned*)(ws + 16384);
    unsigned* cidx = (unsigned*)(ws + 81920);
    unsigned* cntp = (unsigned*)(ws + 147456);
    unsigned short* hist1p = (unsigned short*)(ws + 163840);
    unsigned short* mask16 = (unsigned short*)(ws + 688128);
    unsigned* wbits = (unsigned*)(ws + 1212416);

    k_prep<<<B_ * 256, 256, 0, stream>>>(y, proba, mask16, cntp, hist1p, wbits, cs2, hist2, ccount);
    k_class_sum<<<1024, 256, 0, stream>>>(emb, mask16, cs2);
    k_thresh0<<<B_, 256, 0, stream>>>(hist1p, cntp, ctrl1, cnt);
    k_hist2<<<B_ * 256, 256, 0, stream>>>(wbits, ctrl1, hist2);
    k_thresh1<<<1, 256, 0, stream>>>(hist2, ctrl1, ctrl2);
    k_collect<<<B_ * 256, 256, 0, stream>>>(wbits, ctrl2, ccount, cbits, cidx);
    k_select<<<B_, 64, 0, stream>>>(ccount, cbits, cidx, idxout);
    k_final<<<B_ * K_, 64, 0, stream>>>(emb, y, avg, cs2, cnt, idxout, out);
}

// Round 12
// 121.527 us; speedup vs baseline: 4.2770x; 1.1175x over previous
//
#include <hip/hip_runtime.h>

#define B_ 4
#define C_ 4
#define V_ 262144
#define F_ 64
#define K_ 100
#define THETA 0.9f
#define TAU_ 0.1f
#define CAP2 4096

typedef unsigned long long ull;

// ---------------- workspace layout (bytes) ----------------
// cs2    : 0       .. 8192     (8 replicas x C x F f32; only c=1..3 used)
// cnt    : 8192    .. 8208     (C f32; only 1..3 used)
// ctrl1  : 8208    .. 8240     (B*2 u32: T1, n_above)
// ctrl2  : 8240    .. 8272     (B*2 u32: P16, n_above2)
// ccount : 8272    .. 8288     (B u32)
// idxout : 8320    .. 9920     (B*K u32)
// hist2  : 10240   .. 14336    (B*256 u32)
// cbits  : 16384   .. 81920    (B*CAP2 u32)
// cidx   : 81920   .. 147456   (B*CAP2 u32)
// cntp   : 147456  .. 163840   (1024*4 u32 per-block count partials)
// hist1p : 163840  .. 688128   (1024*256 u16 per-block hist1 partials)
// mask16 : 688128  .. 1212416  (B*V/4 u16 packed class masks; bits 1..3 used)
// wbits  : 1212416 .. 5406720  (B*V u32 product-weight float bits)

// Fused: init + y->mask16/count-partials + proba->wbits/hist1-partials.
// Class 0 is dead in the output (nar = avg_new[:,1:,:]) -> y[b,0,:] never loaded.
__global__ __launch_bounds__(256) void k_prep(const int* __restrict__ y,
                                              const float* __restrict__ proba,
                                              unsigned short* __restrict__ mask16,
                                              unsigned* __restrict__ cntp,
                                              unsigned short* __restrict__ hist1p,
                                              unsigned* __restrict__ wbits,
                                              float* __restrict__ cs2,
                                              unsigned* __restrict__ hist2,
                                              unsigned* __restrict__ ccount) {
    __shared__ unsigned lh[256];
    __shared__ unsigned wc[4][2];
    int blk = blockIdx.x;
    int tid = threadIdx.x;
    int wave = tid >> 6, lane = tid & 63;
    int b = blk >> 8;
    int i4 = ((blk & 255) << 8) | tid;   // float4-group in [0, V/4)

    lh[tid] = 0u;
    // folded init (arrays only consumed by LATER kernels -> no race)
    if (blk < 8) cs2[(blk << 8) | tid] = 0.f;
    else if (blk < 12) hist2[((blk - 8) << 8) | tid] = 0u;
    else if (blk == 12 && tid < 4) ccount[tid] = 0u;
    __syncthreads();

    // ---- y (classes 1..3 only) -> packed masks + per-block counts ----
    const int4* y1 = (const int4*)(y + ((size_t)(b * C_ + 1)) * V_);
    const int4* y2 = (const int4*)(y + ((size_t)(b * C_ + 2)) * V_);
    const int4* y3 = (const int4*)(y + ((size_t)(b * C_ + 3)) * V_);
    int4 yb = y1[i4], yc = y2[i4], yd = y3[i4];

    unsigned n0 = ((unsigned)(yb.x > 0) << 1) | ((unsigned)(yc.x > 0) << 2) | ((unsigned)(yd.x > 0) << 3);
    unsigned n1 = ((unsigned)(yb.y > 0) << 1) | ((unsigned)(yc.y > 0) << 2) | ((unsigned)(yd.y > 0) << 3);
    unsigned n2 = ((unsigned)(yb.z > 0) << 1) | ((unsigned)(yc.z > 0) << 2) | ((unsigned)(yd.z > 0) << 3);
    unsigned n3 = ((unsigned)(yb.w > 0) << 1) | ((unsigned)(yc.w > 0) << 2) | ((unsigned)(yd.w > 0) << 3);
    mask16[(size_t)b * (V_ / 4) + i4] = (unsigned short)(n0 | (n1 << 4) | (n2 << 8) | (n3 << 12));

    unsigned p12 = ((unsigned)(yb.x > 0) + (yb.y > 0) + (yb.z > 0) + (yb.w > 0))
                 | (((unsigned)(yc.x > 0) + (yc.y > 0) + (yc.z > 0) + (yc.w > 0)) << 16);
    unsigned p3 = (unsigned)(yd.x > 0) + (yd.y > 0) + (yd.z > 0) + (yd.w > 0);
    #pragma unroll
    for (int o = 1; o < 64; o <<= 1) {
        p12 += __shfl_xor(p12, o, 64);
        p3 += __shfl_xor(p3, o, 64);
    }
    if (lane == 0) { wc[wave][0] = p12; wc[wave][1] = p3; }

    // ---- proba -> wbits + LDS hist1 ----
    const float* p0 = proba + (size_t)(b * C_) * V_;
    float4 qa = ((const float4*)p0)[i4];
    float4 qb = ((const float4*)(p0 + V_))[i4];
    float4 qc = ((const float4*)(p0 + 2 * V_))[i4];
    float4 qd = ((const float4*)(p0 + 3 * V_))[i4];
    uint4 wb;
    wb.x = __float_as_uint(((qa.x * qb.x) * qc.x) * qd.x);
    wb.y = __float_as_uint(((qa.y * qb.y) * qc.y) * qd.y);
    wb.z = __float_as_uint(((qa.z * qb.z) * qc.z) * qd.z);
    wb.w = __float_as_uint(((qa.w * qb.w) * qc.w) * qd.w);
    ((uint4*)wbits)[(size_t)b * (V_ / 4) + i4] = wb;
    atomicAdd(&lh[wb.x >> 24], 1u);
    atomicAdd(&lh[wb.y >> 24], 1u);
    atomicAdd(&lh[wb.z >> 24], 1u);
    atomicAdd(&lh[wb.w >> 24], 1u);
    __syncthreads();

    hist1p[(blk << 8) | tid] = (unsigned short)lh[tid];
    if (tid == 0) {
        unsigned q12 = wc[0][0] + wc[1][0] + wc[2][0] + wc[3][0];
        unsigned q3 = wc[0][1] + wc[1][1] + wc[2][1] + wc[3][1];
        unsigned* o4 = cntp + (blk << 2);
        o4[0] = 0u; o4[1] = q12 & 0xFFFFu;
        o4[2] = q12 >> 16; o4[3] = q3;
    }
}

// class_sum (c=1..3 only): blocks 0..1023 stream emb; blocks 1024..1027 do
// thresh0 (b = blk-1024); block 1028 reduces cnt partials. (Fusing these
// saves a launch; they only need k_prep outputs — no sync machinery.)
__global__ __launch_bounds__(256) void k_class_sum(const float* __restrict__ emb,
                                                   const unsigned short* __restrict__ mask16,
                                                   float* __restrict__ cs2,
                                                   const unsigned short* __restrict__ hist1p,
                                                   const unsigned* __restrict__ cntp,
                                                   unsigned* __restrict__ ctrl1,
                                                   float* __restrict__ cnt) {
    __shared__ unsigned short smask[16384];   // 32 KB masks for 65536 v
    __shared__ unsigned bins[256];
    __shared__ float wsum[4][4];
    int blk = blockIdx.x;
    int tid = threadIdx.x;
    int wave = tid >> 6, lane = tid & 63;

    if (blk >= 1024) {
        if (blk < 1028) {
            // ---- thresh0 for batch b ----
            int b = blk - 1024;
            unsigned s = 0;
            for (int c = 0; c < 256; ++c)
                s += hist1p[(((b << 8) | c) << 8) | tid];
            bins[tid] = s;
            __syncthreads();
            if (wave == 0) {
                int binbase = 255 - 4 * lane;
                unsigned c0 = bins[binbase], c1 = bins[binbase - 1], c2 = bins[binbase - 2], c3 = bins[binbase - 3];
                unsigned cnt4 = c0 + c1 + c2 + c3;
                unsigned pref = cnt4;
                #pragma unroll
                for (int o = 1; o < 64; o <<= 1) {
                    unsigned u = __shfl_up(pref, o, 64);
                    if (lane >= o) pref += u;
                }
                unsigned above = pref - cnt4;
                unsigned t = above;
                int found = -1; unsigned nab = 0;
                if (t + c0 >= K_)                { found = binbase;     nab = t; }
                else if (t + c0 + c1 >= K_)      { found = binbase - 1; nab = t + c0; }
                else if (t + c0 + c1 + c2 >= K_) { found = binbase - 2; nab = t + c0 + c1; }
                else if (t + cnt4 >= K_)         { found = binbase - 3; nab = t + c0 + c1 + c2; }
                if (found >= 0 && above < K_) {
                    ctrl1[b * 2] = (unsigned)found;
                    ctrl1[b * 2 + 1] = nab;
                }
            }
        } else if (wave == 0) {
            // ---- cnt reduce (classes 1..3; slot 0 stays 0) ----
            unsigned s1 = 0, s2 = 0, s3 = 0;
            #pragma unroll
            for (int r = 0; r < 16; ++r) {
                uint4 p = ((const uint4*)cntp)[(r << 6) | lane];
                s1 += p.y; s2 += p.z; s3 += p.w;
            }
            #pragma unroll
            for (int o = 1; o < 64; o <<= 1) {
                s1 += __shfl_xor(s1, o, 64);
                s2 += __shfl_xor(s2, o, 64);
                s3 += __shfl_xor(s3, o, 64);
            }
            if (lane == 0) {
                cnt[0] = 0.f; cnt[1] = (float)s1;
                cnt[2] = (float)s2; cnt[3] = (float)s3;
            }
        }
        return;
    }

    // ---- streaming path: one contiguous 256KB emb stream per block ----
    int s = blk & 3;
    int f = (blk >> 2) & 63;
    int b = blk >> 8;

    {
        const uint4* msrc = (const uint4*)(mask16 + (size_t)b * (V_ / 4) + (s << 14));
        uint4* mdst = (uint4*)smask;
        #pragma unroll
        for (int i = 0; i < 8; ++i) mdst[(i << 8) | tid] = msrc[(i << 8) | tid];
    }
    __syncthreads();

    const float4* ep = (const float4*)emb + ((size_t)((b << 6) | f)) * (V_ / 4) + ((size_t)s << 14);

    float a1 = 0.f, a2 = 0.f, a3 = 0.f;
    for (int o = 0; o < 8; ++o) {
        float4 e[8];
        unsigned mm[8];
        #pragma unroll
        for (int i = 0; i < 8; ++i) e[i] = ep[(((o << 3) | i) << 8) | tid];
        #pragma unroll
        for (int i = 0; i < 8; ++i) mm[i] = smask[(((o << 3) | i) << 8) | tid];
        #pragma unroll
        for (int i = 0; i < 8; ++i) {
            unsigned m = mm[i];
            float4 ev = e[i];
            a1 += ((m >>  1) & 1u ? ev.x : 0.f) + ((m >>  5) & 1u ? ev.y : 0.f)
                + ((m >>  9) & 1u ? ev.z : 0.f) + ((m >> 13) & 1u ? ev.w : 0.f);
            a2 += ((m >>  2) & 1u ? ev.x : 0.f) + ((m >>  6) & 1u ? ev.y : 0.f)
                + ((m >> 10) & 1u ? ev.z : 0.f) + ((m >> 14) & 1u ? ev.w : 0.f);
            a3 += ((m >>  3) & 1u ? ev.x : 0.f) + ((m >>  7) & 1u ? ev.y : 0.f)
                + ((m >> 11) & 1u ? ev.z : 0.f) + ((m >> 15) & 1u ? ev.w : 0.f);
        }
    }
    #pragma unroll
    for (int o = 1; o < 64; o <<= 1) {
        a1 += __shfl_xor(a1, o, 64);
        a2 += __shfl_xor(a2, o, 64);
        a3 += __shfl_xor(a3, o, 64);
    }
    if (lane == 0) { wsum[wave][0] = a1; wsum[wave][1] = a2; wsum[wave][2] = a3; }
    __syncthreads();
    if (tid < 3) {
        float v = wsum[0][tid] + wsum[1][tid] + wsum[2][tid] + wsum[3][tid];
        atomicAdd(&cs2[((blk & 7) << 8) | ((tid + 1) << 6) | f], v);   // <=4-deep chains
    }
}

// level-2 histogram: next 8 bits, only for elements in bin T1 (reads wbits)
__global__ __launch_bounds__(256) void k_hist2(const unsigned* __restrict__ wbits,
                                               const unsigned* __restrict__ ctrl1,
                                               unsigned* __restrict__ hist2) {
    __shared__ unsigned lh[256];
    int tid = threadIdx.x;
    lh[tid] = 0u;
    __syncthreads();
    int b = blockIdx.x >> 8;
    int base = (blockIdx.x & 255) << 10;
    unsigned T1 = ctrl1[b * 2];
    for (int it = 0; it < 4; ++it) {
        int v = base + tid + (it << 8);
        unsigned bits = wbits[(size_t)b * V_ + v];
        if ((bits >> 24) == T1) atomicAdd(&lh[(bits >> 16) & 0xFF], 1u);
    }
    __syncthreads();
    if (lh[tid]) atomicAdd(&hist2[b * 256 + tid], lh[tid]);  // sparse, shallow chains
}

// second-level threshold: P16 = (T1<<8)|T2
__global__ __launch_bounds__(256) void k_thresh1(const unsigned* __restrict__ hist,
                                                 const unsigned* __restrict__ ctrl_in,
                                                 unsigned* __restrict__ ctrl_out) {
    int b = threadIdx.x >> 6;
    int lane = threadIdx.x & 63;
    const unsigned* h = hist + b * 256;
    unsigned base = ctrl_in[b * 2 + 1];
    int binbase = 255 - 4 * lane;
    unsigned c0 = h[binbase], c1 = h[binbase - 1], c2 = h[binbase - 2], c3 = h[binbase - 3];
    unsigned cnt4 = c0 + c1 + c2 + c3;
    unsigned pref = cnt4;
    #pragma unroll
    for (int o = 1; o < 64; o <<= 1) {
        unsigned u = __shfl_up(pref, o, 64);
        if (lane >= o) pref += u;
    }
    unsigned above = base + pref - cnt4;
    unsigned t = above;
    int found = -1; unsigned nab = 0;
    if (t + c0 >= K_)                { found = binbase;     nab = t; }
    else if (t + c0 + c1 >= K_)      { found = binbase - 1; nab = t + c0; }
    else if (t + c0 + c1 + c2 >= K_) { found = binbase - 2; nab = t + c0 + c1; }
    else if (t + cnt4 >= K_)         { found = binbase - 3; nab = t + c0 + c1 + c2; }
    if (found >= 0 && above < K_) {
        ctrl_out[b * 2] = (ctrl_in[b * 2] << 8) | (unsigned)found;
        ctrl_out[b * 2 + 1] = nab;
    }
}

// collect all candidates with (bits>>16) >= P16
__global__ __launch_bounds__(256) void k_collect(const unsigned* __restrict__ wbits,
                                                 const unsigned* __restrict__ ctrl2,
                                                 unsigned* __restrict__ ccount,
                                                 unsigned* __restrict__ cbits,
                                                 unsigned* __restrict__ cidx) {
    int b = blockIdx.x >> 8;
    int base = (blockIdx.x & 255) << 10;
    int tid = threadIdx.x;
    unsigned P16 = ctrl2[b * 2];
    for (int it = 0; it < 4; ++it) {
        int v = base + tid + (it << 8);
        unsigned bits = wbits[(size_t)b * V_ + v];
        if ((bits >> 16) >= P16) {
            unsigned pos = atomicAdd(&ccount[b], 1u);
            if (pos < CAP2) { cbits[b * CAP2 + pos] = bits; cidx[b * CAP2 + pos] = (unsigned)v; }
        }
    }
}

// exact top-K: one wave per b, lane-private LDS regions, zero barriers.
__global__ __launch_bounds__(64) void k_select(const unsigned* __restrict__ ccount,
                                               const unsigned* __restrict__ cbits,
                                               const unsigned* __restrict__ cidx,
                                               unsigned* __restrict__ idxout) {
    __shared__ ull keys[CAP2];
    int b = blockIdx.x;
    int lane = threadIdx.x;
    unsigned nc = ccount[b];
    int n = (int)(nc < CAP2 ? nc : CAP2);
    for (int i = lane; i < n; i += 64)
        keys[i] = ((ull)cbits[b * CAP2 + i] << 32) | (unsigned)(~cidx[b * CAP2 + i]);
    for (int k = 0; k < K_; ++k) {
        ull m = 0ull; int mslot = -1;
        for (int i = lane; i < n; i += 64) {
            ull key = keys[i];
            if (key > m) { m = key; mslot = i; }
        }
        ull lm = m;
        #pragma unroll
        for (int o = 1; o < 64; o <<= 1) {
            ull other = __shfl_xor(m, o, 64);
            if (other > m) m = other;
        }
        if (mslot >= 0 && lm == m) keys[mslot] = 0ull;
        if (lane == 0) idxout[b * K_ + k] = ~(unsigned)(m & 0xFFFFFFFFull);
    }
}

// final: one wave (64 lanes = F) per (b,k); sums the 8 cs replicas inline.
__global__ __launch_bounds__(64) void k_final(const float* __restrict__ emb,
                                              const int* __restrict__ y,
                                              const float* __restrict__ avg,
                                              const float* __restrict__ cs2,
                                              const float* __restrict__ cnt,
                                              const unsigned* __restrict__ idxout,
                                              float* __restrict__ out) {
    int blk = blockIdx.x;
    int b = blk / K_;
    int k = blk % K_;
    int lane = threadIdx.x;
    unsigned v = idxout[b * K_ + k];

    float e = emb[((size_t)(b * F_ + lane)) * V_ + v];

    int y0v = y[((size_t)(b * C_ + 0)) * V_ + v];
    int y1v = y[((size_t)(b * C_ + 1)) * V_ + v];
    int y2v = y[((size_t)(b * C_ + 2)) * V_ + v];
    int y3v = y[((size_t)(b * C_ + 3)) * V_ + v];
    int cm = (y0v > 0) ? 0 : ((y1v > 0) ? 1 : ((y2v > 0) ? 2 : ((y3v > 0) ? 3 : 0)));
    float sel = (cm == 0) ? 1.f : 0.f;

    float t = e / TAU_;
    float ssum = 0.f;
    #pragma unroll
    for (int c = 1; c < 4; ++c) {
        float cc = cnt[c];
        float csum = 0.f;
        #pragma unroll
        for (int rep = 0; rep < 8; ++rep) csum += cs2[(rep << 8) | (c << 6) | lane];
        float mean = csum / fmaxf(cc, 1.f);
        float av = avg[c * F_ + lane];
        float nar = (cc > 0.f) ? (av * (1.f - THETA) + mean * THETA) : av;
        ssum += expf(t * nar);
    }
    float term = -logf(ssum);
    #pragma unroll
    for (int o = 32; o > 0; o >>= 1) term += __shfl_down(term, o, 64);
    if (lane == 0) out[b * K_ + k] = term * sel;
}

extern "C" void kernel_launch(void* const* d_in, const int* in_sizes, int n_in,
                              void* d_out, int out_size, void* d_ws, size_t ws_size,
                              hipStream_t stream) {
    const float* proba = (const float*)d_in[0];
    const int* y = (const int*)d_in[1];
    const float* emb = (const float*)d_in[2];
    const float* avg = (const float*)d_in[3];
    float* out = (float*)d_out;

    char* ws = (char*)d_ws;
    float* cs2 = (float*)(ws + 0);
    float* cnt = (float*)(ws + 8192);
    unsigned* ctrl1 = (unsigned*)(ws + 8208);
    unsigned* ctrl2 = (unsigned*)(ws + 8240);
    unsigned* ccount = (unsigned*)(ws + 8272);
    unsigned* idxout = (unsigned*)(ws + 8320);
    unsigned* hist2 = (unsigned*)(ws + 10240);
    unsigned* cbits = (unsigned*)(ws + 16384);
    unsigned* cidx = (unsigned*)(ws + 81920);
    unsigned* cntp = (unsigned*)(ws + 147456);
    unsigned short* hist1p = (unsigned short*)(ws + 163840);
    unsigned short* mask16 = (unsigned short*)(ws + 688128);
    unsigned* wbits = (unsigned*)(ws + 1212416);

    k_prep<<<B_ * 256, 256, 0, stream>>>(y, proba, mask16, cntp, hist1p, wbits, cs2, hist2, ccount);
    k_class_sum<<<1029, 256, 0, stream>>>(emb, mask16, cs2, hist1p, cntp, ctrl1, cnt);
    k_hist2<<<B_ * 256, 256, 0, stream>>>(wbits, ctrl1, hist2);
    k_thresh1<<<1, 256, 0, stream>>>(hist2, ctrl1, ctrl2);
    k_collect<<<B_ * 256, 256, 0, stream>>>(wbits, ctrl2, ccount, cbits, cidx);
    k_select<<<B_, 64, 0, stream>>>(ccount, cbits, cidx, idxout);
    k_final<<<B_ * K_, 64, 0, stream>>>(emb, y, avg, cs2, cnt, idxout, out);
}

// Round 13
// 79.059 us; speedup vs baseline: 6.5744x; 1.5372x over previous
//
#include <hip/hip_runtime.h>

#define B_ 4
#define C_ 4
#define V_ 262144
#define F_ 64
#define K_ 100
#define THETA 0.9f
#define TAU_ 0.1f

typedef unsigned long long ull;

// ---------------- workspace layout (bytes) ----------------
// cs2    : 0       .. 8192     (8 replicas x C x F f32; only c=1..3 used)
// cnt    : 8192    .. 8208     (C f32; only 1..3 used)
// ctrl1  : 8208    .. 8240     (B*2 u32: T1, n_above)
// idxout : 8320    .. 9920     (B*K u32)
// cntp   : 147456  .. 163840   (1024*4 u32 count partials)  [prep->class_sum]
// cntblk : 147456  .. 151552   (B*256 u32 slot counts)      [collect->select, REUSES cntp]
// hist1p : 163840  .. 688128   (1024*256 u16 hist partials) [prep->class_sum]
// sbits  : 163840  .. 425984   (B*256*64 u32 slot bits)     [collect->select, REUSES hist1p]
// sidx   : 425984  .. 688128   (B*256*64 u32 slot idx)      [collect->select, REUSES hist1p]
// mask16 : 688128  .. 1212416  (B*V/4 u16 packed class masks; bits 1..3)
// wbits  : 1212416 .. 5406720  (B*V u32 product-weight float bits)
// Region reuse is safe: hist1p/cntp are fully rewritten by k_prep and consumed
// by k_class_sum's tail blocks BEFORE k_collect overwrites them (serial stream).

// Fused: init + y->mask16/count-partials + proba->wbits/hist1-partials.
__global__ __launch_bounds__(256) void k_prep(const int* __restrict__ y,
                                              const float* __restrict__ proba,
                                              unsigned short* __restrict__ mask16,
                                              unsigned* __restrict__ cntp,
                                              unsigned short* __restrict__ hist1p,
                                              unsigned* __restrict__ wbits,
                                              float* __restrict__ cs2) {
    __shared__ unsigned lh[256];
    __shared__ unsigned wc[4][2];
    int blk = blockIdx.x;
    int tid = threadIdx.x;
    int wave = tid >> 6, lane = tid & 63;
    int b = blk >> 8;
    int i4 = ((blk & 255) << 8) | tid;   // float4-group in [0, V/4)

    lh[tid] = 0u;
    if (blk < 8) cs2[(blk << 8) | tid] = 0.f;   // folded init (consumed later)
    __syncthreads();

    // ---- y (classes 1..3 only; class 0 dead in output) -> masks + counts ----
    const int4* y1 = (const int4*)(y + ((size_t)(b * C_ + 1)) * V_);
    const int4* y2 = (const int4*)(y + ((size_t)(b * C_ + 2)) * V_);
    const int4* y3 = (const int4*)(y + ((size_t)(b * C_ + 3)) * V_);
    int4 yb = y1[i4], yc = y2[i4], yd = y3[i4];

    unsigned n0 = ((unsigned)(yb.x > 0) << 1) | ((unsigned)(yc.x > 0) << 2) | ((unsigned)(yd.x > 0) << 3);
    unsigned n1 = ((unsigned)(yb.y > 0) << 1) | ((unsigned)(yc.y > 0) << 2) | ((unsigned)(yd.y > 0) << 3);
    unsigned n2 = ((unsigned)(yb.z > 0) << 1) | ((unsigned)(yc.z > 0) << 2) | ((unsigned)(yd.z > 0) << 3);
    unsigned n3 = ((unsigned)(yb.w > 0) << 1) | ((unsigned)(yc.w > 0) << 2) | ((unsigned)(yd.w > 0) << 3);
    mask16[(size_t)b * (V_ / 4) + i4] = (unsigned short)(n0 | (n1 << 4) | (n2 << 8) | (n3 << 12));

    unsigned p12 = ((unsigned)(yb.x > 0) + (yb.y > 0) + (yb.z > 0) + (yb.w > 0))
                 | (((unsigned)(yc.x > 0) + (yc.y > 0) + (yc.z > 0) + (yc.w > 0)) << 16);
    unsigned p3 = (unsigned)(yd.x > 0) + (yd.y > 0) + (yd.z > 0) + (yd.w > 0);
    #pragma unroll
    for (int o = 1; o < 64; o <<= 1) {
        p12 += __shfl_xor(p12, o, 64);
        p3 += __shfl_xor(p3, o, 64);
    }
    if (lane == 0) { wc[wave][0] = p12; wc[wave][1] = p3; }

    // ---- proba -> wbits + LDS hist1 ----
    const float* p0 = proba + (size_t)(b * C_) * V_;
    float4 qa = ((const float4*)p0)[i4];
    float4 qb = ((const float4*)(p0 + V_))[i4];
    float4 qc = ((const float4*)(p0 + 2 * V_))[i4];
    float4 qd = ((const float4*)(p0 + 3 * V_))[i4];
    uint4 wb;
    wb.x = __float_as_uint(((qa.x * qb.x) * qc.x) * qd.x);
    wb.y = __float_as_uint(((qa.y * qb.y) * qc.y) * qd.y);
    wb.z = __float_as_uint(((qa.z * qb.z) * qc.z) * qd.z);
    wb.w = __float_as_uint(((qa.w * qb.w) * qc.w) * qd.w);
    ((uint4*)wbits)[(size_t)b * (V_ / 4) + i4] = wb;
    atomicAdd(&lh[wb.x >> 24], 1u);
    atomicAdd(&lh[wb.y >> 24], 1u);
    atomicAdd(&lh[wb.z >> 24], 1u);
    atomicAdd(&lh[wb.w >> 24], 1u);
    __syncthreads();

    hist1p[(blk << 8) | tid] = (unsigned short)lh[tid];
    if (tid == 0) {
        unsigned q12 = wc[0][0] + wc[1][0] + wc[2][0] + wc[3][0];
        unsigned q3 = wc[0][1] + wc[1][1] + wc[2][1] + wc[3][1];
        unsigned* o4 = cntp + (blk << 2);
        o4[0] = 0u; o4[1] = q12 & 0xFFFFu;
        o4[2] = q12 >> 16; o4[3] = q3;
    }
}

// class_sum (c=1..3): blocks 0..1023 stream emb; 1024..1027 thresh0; 1028 cnt.
__global__ __launch_bounds__(256) void k_class_sum(const float* __restrict__ emb,
                                                   const unsigned short* __restrict__ mask16,
                                                   float* __restrict__ cs2,
                                                   const unsigned short* __restrict__ hist1p,
                                                   const unsigned* __restrict__ cntp,
                                                   unsigned* __restrict__ ctrl1,
                                                   float* __restrict__ cnt) {
    __shared__ unsigned short smask[16384];
    __shared__ unsigned bins[256];
    __shared__ float wsum[4][4];
    int blk = blockIdx.x;
    int tid = threadIdx.x;
    int wave = tid >> 6, lane = tid & 63;

    if (blk >= 1024) {
        if (blk < 1028) {
            int b = blk - 1024;
            unsigned s = 0;
            for (int c = 0; c < 256; ++c)
                s += hist1p[(((b << 8) | c) << 8) | tid];
            bins[tid] = s;
            __syncthreads();
            if (wave == 0) {
                int binbase = 255 - 4 * lane;
                unsigned c0 = bins[binbase], c1 = bins[binbase - 1], c2 = bins[binbase - 2], c3 = bins[binbase - 3];
                unsigned cnt4 = c0 + c1 + c2 + c3;
                unsigned pref = cnt4;
                #pragma unroll
                for (int o = 1; o < 64; o <<= 1) {
                    unsigned u = __shfl_up(pref, o, 64);
                    if (lane >= o) pref += u;
                }
                unsigned above = pref - cnt4;
                unsigned t = above;
                int found = -1; unsigned nab = 0;
                if (t + c0 >= K_)                { found = binbase;     nab = t; }
                else if (t + c0 + c1 >= K_)      { found = binbase - 1; nab = t + c0; }
                else if (t + c0 + c1 + c2 >= K_) { found = binbase - 2; nab = t + c0 + c1; }
                else if (t + cnt4 >= K_)         { found = binbase - 3; nab = t + c0 + c1 + c2; }
                if (found >= 0 && above < K_) {
                    ctrl1[b * 2] = (unsigned)found;
                    ctrl1[b * 2 + 1] = nab;
                }
            }
        } else if (wave == 0) {
            unsigned s1 = 0, s2 = 0, s3 = 0;
            #pragma unroll
            for (int r = 0; r < 16; ++r) {
                uint4 p = ((const uint4*)cntp)[(r << 6) | lane];
                s1 += p.y; s2 += p.z; s3 += p.w;
            }
            #pragma unroll
            for (int o = 1; o < 64; o <<= 1) {
                s1 += __shfl_xor(s1, o, 64);
                s2 += __shfl_xor(s2, o, 64);
                s3 += __shfl_xor(s3, o, 64);
            }
            if (lane == 0) {
                cnt[0] = 0.f; cnt[1] = (float)s1;
                cnt[2] = (float)s2; cnt[3] = (float)s3;
            }
        }
        return;
    }

    int s = blk & 3;
    int f = (blk >> 2) & 63;
    int b = blk >> 8;

    {
        const uint4* msrc = (const uint4*)(mask16 + (size_t)b * (V_ / 4) + (s << 14));
        uint4* mdst = (uint4*)smask;
        #pragma unroll
        for (int i = 0; i < 8; ++i) mdst[(i << 8) | tid] = msrc[(i << 8) | tid];
    }
    __syncthreads();

    const float4* ep = (const float4*)emb + ((size_t)((b << 6) | f)) * (V_ / 4) + ((size_t)s << 14);

    float a1 = 0.f, a2 = 0.f, a3 = 0.f;
    for (int o = 0; o < 8; ++o) {
        float4 e[8];
        unsigned mm[8];
        #pragma unroll
        for (int i = 0; i < 8; ++i) e[i] = ep[(((o << 3) | i) << 8) | tid];
        #pragma unroll
        for (int i = 0; i < 8; ++i) mm[i] = smask[(((o << 3) | i) << 8) | tid];
        #pragma unroll
        for (int i = 0; i < 8; ++i) {
            unsigned m = mm[i];
            float4 ev = e[i];
            a1 += ((m >>  1) & 1u ? ev.x : 0.f) + ((m >>  5) & 1u ? ev.y : 0.f)
                + ((m >>  9) & 1u ? ev.z : 0.f) + ((m >> 13) & 1u ? ev.w : 0.f);
            a2 += ((m >>  2) & 1u ? ev.x : 0.f) + ((m >>  6) & 1u ? ev.y : 0.f)
                + ((m >> 10) & 1u ? ev.z : 0.f) + ((m >> 14) & 1u ? ev.w : 0.f);
            a3 += ((m >>  3) & 1u ? ev.x : 0.f) + ((m >>  7) & 1u ? ev.y : 0.f)
                + ((m >> 11) & 1u ? ev.z : 0.f) + ((m >> 15) & 1u ? ev.w : 0.f);
        }
    }
    #pragma unroll
    for (int o = 1; o < 64; o <<= 1) {
        a1 += __shfl_xor(a1, o, 64);
        a2 += __shfl_xor(a2, o, 64);
        a3 += __shfl_xor(a3, o, 64);
    }
    if (lane == 0) { wsum[wave][0] = a1; wsum[wave][1] = a2; wsum[wave][2] = a3; }
    __syncthreads();
    if (tid < 3) {
        float v = wsum[0][tid] + wsum[1][tid] + wsum[2][tid] + wsum[3][tid];
        atomicAdd(&cs2[((blk & 7) << 8) | ((tid + 1) << 6) | f], v);
    }
}

// T1-level collect into per-block fixed slots (NO global atomics).
// Measured candidate stats (r0-r12): ~300-400/batch total -> ~1.5/block avg.
__global__ __launch_bounds__(256) void k_collect(const unsigned* __restrict__ wbits,
                                                 const unsigned* __restrict__ ctrl1,
                                                 unsigned* __restrict__ cntblk,
                                                 unsigned* __restrict__ sbits,
                                                 unsigned* __restrict__ sidx) {
    __shared__ unsigned lcnt;
    int blk = blockIdx.x;
    int b = blk >> 8;
    int cb = blk & 255;
    int tid = threadIdx.x;
    if (tid == 0) lcnt = 0u;
    __syncthreads();
    unsigned T1 = ctrl1[b * 2];
    int base = cb << 10;
    int sb = ((b << 8) | cb) << 6;
    #pragma unroll
    for (int it = 0; it < 4; ++it) {
        int v = base + tid + (it << 8);
        unsigned bits = wbits[(size_t)b * V_ + v];
        if ((bits >> 24) >= T1) {
            unsigned pos = atomicAdd(&lcnt, 1u);   // LDS atomic, shallow
            if (pos < 64u) { sbits[sb | pos] = bits; sidx[sb | pos] = (unsigned)v; }
        }
    }
    __syncthreads();
    if (tid == 0) cntblk[(b << 8) | cb] = (lcnt < 64u) ? lcnt : 64u;
}

// bitonic compare-exchange (descending, 512 virtual lanes, 8 keys/lane)
#define XSTEP(kk_, k_, j_) { \
    _Pragma("unroll") \
    for (int r = 0; r < 8; ++r) { \
        ull o = __shfl_xor(kk_[r], (j_) >> 3, 64); \
        int p = (lane << 3) | r; \
        bool keepmax = (((p & (k_)) == 0) == ((p & (j_)) == 0)); \
        kk_[r] = (keepmax == (kk_[r] > o)) ? kk_[r] : o; \
    } }
#define LSTEP(kk_, k_, j_) { \
    _Pragma("unroll") \
    for (int r = 0; r < 8; ++r) { \
        if (!(r & (j_))) { \
            int p = (lane << 3) | r; \
            bool up = ((p & (k_)) == 0); \
            ull a = kk_[r], c = kk_[r | (j_)]; \
            ull mx = a > c ? a : c, mn = a > c ? c : a; \
            kk_[r] = up ? mx : mn; \
            kk_[r | (j_)] = up ? mn : mx; \
        } \
    } }

// Fused refine+select: per batch, LDS hist2 -> P16 -> filter (~150) -> bitonic.
// Replaces k_hist2 + k_thresh1 + old k_select (2 launches + 4MB re-read gone).
__global__ __launch_bounds__(256) void k_select(const unsigned* __restrict__ ctrl1,
                                                const unsigned* __restrict__ cntblk,
                                                const unsigned* __restrict__ sbits,
                                                const unsigned* __restrict__ sidx,
                                                unsigned* __restrict__ idxout) {
    __shared__ unsigned hist[256];
    __shared__ ull keys[512];
    __shared__ unsigned P16s, fcnt;
    int b = blockIdx.x;
    int tid = threadIdx.x;
    int wave = tid >> 6, lane = tid & 63;
    unsigned T1 = ctrl1[b * 2];
    unsigned nab = ctrl1[b * 2 + 1];

    hist[tid] = 0u;
    keys[tid] = 0ull;
    keys[tid + 256] = 0ull;
    if (tid == 0) fcnt = 0u;
    __syncthreads();

    int c = (int)cntblk[(b << 8) | tid];   // thread t owns source chunk t
    int sb = ((b << 8) | tid) << 6;
    for (int i = 0; i < c; ++i) {
        unsigned bits = sbits[sb | i];
        if ((bits >> 24) == T1) atomicAdd(&hist[(bits >> 16) & 0xFF], 1u);
    }
    __syncthreads();

    if (wave == 0) {   // descending scan -> T2 -> P16
        int binbase = 255 - 4 * lane;
        unsigned c0 = hist[binbase], c1 = hist[binbase - 1], c2 = hist[binbase - 2], c3 = hist[binbase - 3];
        unsigned cnt4 = c0 + c1 + c2 + c3;
        unsigned pref = cnt4;
        #pragma unroll
        for (int o = 1; o < 64; o <<= 1) {
            unsigned u = __shfl_up(pref, o, 64);
            if (lane >= o) pref += u;
        }
        unsigned above = nab + pref - cnt4;
        unsigned t = above;
        int found = -1;
        if (t + c0 >= K_)                { found = binbase;     }
        else if (t + c0 + c1 >= K_)      { found = binbase - 1; }
        else if (t + c0 + c1 + c2 >= K_) { found = binbase - 2; }
        else if (t + cnt4 >= K_)         { found = binbase - 3; }
        if (found >= 0 && above < K_) P16s = (T1 << 8) | (unsigned)found;
    }
    __syncthreads();

    unsigned P16 = P16s;
    for (int i = 0; i < c; ++i) {
        unsigned bits = sbits[sb | i];
        if ((bits >> 16) >= P16) {
            unsigned pos = atomicAdd(&fcnt, 1u);   // ~150 total, LDS, shallow
            if (pos < 512u) keys[pos] = ((ull)bits << 32) | (unsigned)(~sidx[sb | i]);
        }
    }
    __syncthreads();

    if (wave == 0) {   // exact (bits desc, idx asc) == lax.top_k order
        ull kk[8];
        #pragma unroll
        for (int r = 0; r < 8; ++r) kk[r] = keys[(lane << 3) | r];
        LSTEP(kk, 2, 1)
        LSTEP(kk, 4, 2) LSTEP(kk, 4, 1)
        LSTEP(kk, 8, 4) LSTEP(kk, 8, 2) LSTEP(kk, 8, 1)
        XSTEP(kk, 16, 8) LSTEP(kk, 16, 4) LSTEP(kk, 16, 2) LSTEP(kk, 16, 1)
        XSTEP(kk, 32, 16) XSTEP(kk, 32, 8) LSTEP(kk, 32, 4) LSTEP(kk, 32, 2) LSTEP(kk, 32, 1)
        XSTEP(kk, 64, 32) XSTEP(kk, 64, 16) XSTEP(kk, 64, 8) LSTEP(kk, 64, 4) LSTEP(kk, 64, 2) LSTEP(kk, 64, 1)
        XSTEP(kk, 128, 64) XSTEP(kk, 128, 32) XSTEP(kk, 128, 16) XSTEP(kk, 128, 8) LSTEP(kk, 128, 4) LSTEP(kk, 128, 2) LSTEP(kk, 128, 1)
        XSTEP(kk, 256, 128) XSTEP(kk, 256, 64) XSTEP(kk, 256, 32) XSTEP(kk, 256, 16) XSTEP(kk, 256, 8) LSTEP(kk, 256, 4) LSTEP(kk, 256, 2) LSTEP(kk, 256, 1)
        XSTEP(kk, 512, 256) XSTEP(kk, 512, 128) XSTEP(kk, 512, 64) XSTEP(kk, 512, 32) XSTEP(kk, 512, 16) XSTEP(kk, 512, 8) LSTEP(kk, 512, 4) LSTEP(kk, 512, 2) LSTEP(kk, 512, 1)
        #pragma unroll
        for (int r = 0; r < 8; ++r) {
            int p = (lane << 3) | r;
            if (p < K_) idxout[b * K_ + p] = ~(unsigned)(kk[r] & 0xFFFFFFFFull);
        }
    }
}

// final: one wave (64 lanes = F) per (b,k); sums the 8 cs replicas inline.
__global__ __launch_bounds__(64) void k_final(const float* __restrict__ emb,
                                              const int* __restrict__ y,
                                              const float* __restrict__ avg,
                                              const float* __restrict__ cs2,
                                              const float* __restrict__ cnt,
                                              const unsigned* __restrict__ idxout,
                                              float* __restrict__ out) {
    int blk = blockIdx.x;
    int b = blk / K_;
    int k = blk % K_;
    int lane = threadIdx.x;
    unsigned v = idxout[b * K_ + k];

    float e = emb[((size_t)(b * F_ + lane)) * V_ + v];

    int y0v = y[((size_t)(b * C_ + 0)) * V_ + v];
    int y1v = y[((size_t)(b * C_ + 1)) * V_ + v];
    int y2v = y[((size_t)(b * C_ + 2)) * V_ + v];
    int y3v = y[((size_t)(b * C_ + 3)) * V_ + v];
    int cm = (y0v > 0) ? 0 : ((y1v > 0) ? 1 : ((y2v > 0) ? 2 : ((y3v > 0) ? 3 : 0)));
    float sel = (cm == 0) ? 1.f : 0.f;

    float t = e / TAU_;
    float ssum = 0.f;
    #pragma unroll
    for (int c = 1; c < 4; ++c) {
        float cc = cnt[c];
        float csum = 0.f;
        #pragma unroll
        for (int rep = 0; rep < 8; ++rep) csum += cs2[(rep << 8) | (c << 6) | lane];
        float mean = csum / fmaxf(cc, 1.f);
        float av = avg[c * F_ + lane];
        float nar = (cc > 0.f) ? (av * (1.f - THETA) + mean * THETA) : av;
        ssum += expf(t * nar);
    }
    float term = -logf(ssum);
    #pragma unroll
    for (int o = 32; o > 0; o >>= 1) term += __shfl_down(term, o, 64);
    if (lane == 0) out[b * K_ + k] = term * sel;
}

extern "C" void kernel_launch(void* const* d_in, const int* in_sizes, int n_in,
                              void* d_out, int out_size, void* d_ws, size_t ws_size,
                              hipStream_t stream) {
    const float* proba = (const float*)d_in[0];
    const int* y = (const int*)d_in[1];
    const float* emb = (const float*)d_in[2];
    const float* avg = (const float*)d_in[3];
    float* out = (float*)d_out;

    char* ws = (char*)d_ws;
    float* cs2 = (float*)(ws + 0);
    float* cnt = (float*)(ws + 8192);
    unsigned* ctrl1 = (unsigned*)(ws + 8208);
    unsigned* idxout = (unsigned*)(ws + 8320);
    unsigned* cntp = (unsigned*)(ws + 147456);
    unsigned* cntblk = (unsigned*)(ws + 147456);          // reuse cntp
    unsigned short* hist1p = (unsigned short*)(ws + 163840);
    unsigned* sbits = (unsigned*)(ws + 163840);           // reuse hist1p
    unsigned* sidx = (unsigned*)(ws + 425984);            // reuse hist1p
    unsigned short* mask16 = (unsigned short*)(ws + 688128);
    unsigned* wbits = (unsigned*)(ws + 1212416);

    k_prep<<<B_ * 256, 256, 0, stream>>>(y, proba, mask16, cntp, hist1p, wbits, cs2);
    k_class_sum<<<1029, 256, 0, stream>>>(emb, mask16, cs2, hist1p, cntp, ctrl1, cnt);
    k_collect<<<B_ * 256, 256, 0, stream>>>(wbits, ctrl1, cntblk, sbits, sidx);
    k_select<<<B_, 256, 0, stream>>>(ctrl1, cntblk, sbits, sidx, idxout);
    k_final<<<B_ * K_, 64, 0, stream>>>(emb, y, avg, cs2, cnt, idxout, out);
}